// Round 1
// baseline (397.839 us; speedup 1.0000x reference)
//
#include <hip/hip_runtime.h>

#define D_FEAT 1024
#define NTOK   4096
#define SEQ    2048
#define NHEAD  16
#define DK     64
#define SPST   72   // sP row stride (ushorts): 144B, 16B-aligned, cuts write conflicts

typedef float          f32x4 __attribute__((ext_vector_type(4)));
typedef short          s16x8 __attribute__((ext_vector_type(8)));
typedef unsigned short u16x4 __attribute__((ext_vector_type(4)));

__device__ __forceinline__ unsigned short f2bf(float f) {
  union { float f; unsigned int u; } x; x.f = f;
  unsigned int r = x.u + 0x7fffu + ((x.u >> 16) & 1u);
  return (unsigned short)(r >> 16);
}

__device__ __forceinline__ f32x4 mfma16(s16x8 a, s16x8 b, f32x4 c) {
  return __builtin_amdgcn_mfma_f32_16x16x32_bf16(a, b, c, 0, 0, 0);
}

// ---------------- cast fp32 -> bf16 for q,k,v ----------------
__global__ __launch_bounds__(256) void cast_bf16_kernel(
    const float* __restrict__ q, const float* __restrict__ k, const float* __restrict__ v,
    unsigned short* __restrict__ qb, unsigned short* __restrict__ kb, unsigned short* __restrict__ vb)
{
  int sel = blockIdx.y;
  const float* src = sel == 0 ? q : (sel == 1 ? k : v);
  unsigned short* dst = sel == 0 ? qb : (sel == 1 ? kb : vb);
  size_t i = ((size_t)blockIdx.x * 256 + threadIdx.x) * 4;
  float4 f = *(const float4*)(src + i);
  u16x4 o; o.x = f2bf(f.x); o.y = f2bf(f.y); o.z = f2bf(f.z); o.w = f2bf(f.w);
  *(u16x4*)(dst + i) = o;
}

// ---------------- transpose + cast weights: W (K x N) fp32 -> Wt (N x K) bf16 ----------------
__global__ __launch_bounds__(256) void transpose_cast_kernel(
    const float* __restrict__ W0, const float* __restrict__ W1,
    const float* __restrict__ W2, const float* __restrict__ W3,
    unsigned short* __restrict__ T0, unsigned short* __restrict__ T1,
    unsigned short* __restrict__ T2, unsigned short* __restrict__ T3)
{
  __shared__ float tile[32][33];
  int z = blockIdx.z;
  const float* W = z == 0 ? W0 : z == 1 ? W1 : z == 2 ? W2 : W3;
  unsigned short* T = z == 0 ? T0 : z == 1 ? T1 : z == 2 ? T2 : T3;
  int tx = threadIdx.x, ty = threadIdx.y;
  int n = blockIdx.x * 32 + tx;
  for (int i = 0; i < 4; ++i) {
    int k = blockIdx.y * 32 + ty + i * 8;
    tile[ty + i * 8][tx] = W[(size_t)k * D_FEAT + n];
  }
  __syncthreads();
  int k = blockIdx.y * 32 + tx;
  for (int i = 0; i < 4; ++i) {
    int n2 = blockIdx.x * 32 + ty + i * 8;
    T[(size_t)n2 * D_FEAT + k] = f2bf(tile[tx][ty + i * 8]);
  }
}

// ---------------- TN GEMM: C(MxN) = A(MxK,bf16) * Bt(NxK,bf16)^T + bias [+resid] ----------------
// MODE 0: bf16 output (projections). MODE 1: fp32 output + residual (out proj).
template <int MODE>
__global__ __launch_bounds__(256) void gemm_tn(
    const unsigned short* __restrict__ A,
    const unsigned short* __restrict__ Bt,
    const float* __restrict__ bias,
    const float* __restrict__ resid,
    void* __restrict__ Cout,
    int M, int N, int K)
{
  __shared__ __align__(16) unsigned short sA[128 * 32];
  __shared__ __align__(16) unsigned short sB[128 * 32];
  const int tid = threadIdx.x;
  const int wave = tid >> 6, lane = tid & 63;
  const int quad = lane >> 4, l16 = lane & 15;
  const int wx = wave & 1, wy = wave >> 1;
  const int n0 = blockIdx.x * 128, m0 = blockIdx.y * 128;

  f32x4 acc[4][4];
  for (int mt = 0; mt < 4; ++mt)
    for (int nt = 0; nt < 4; ++nt) acc[mt][nt] = (f32x4){0.f, 0.f, 0.f, 0.f};

  for (int k0 = 0; k0 < K; k0 += 32) {
    __syncthreads();
    for (int i = 0; i < 2; ++i) {
      int c = tid + 256 * i;
      int row = c >> 2, col = (c & 3) * 8;
      *(s16x8*)(sA + row * 32 + col) =
          *(const s16x8*)(A + (size_t)(m0 + row) * K + k0 + col);
    }
    for (int i = 0; i < 2; ++i) {
      int c = tid + 256 * i;
      int row = c >> 2, col = (c & 3) * 8;
      *(s16x8*)(sB + row * 32 + col) =
          *(const s16x8*)(Bt + (size_t)(n0 + row) * K + k0 + col);
    }
    __syncthreads();
    s16x8 af[4], bfr[4];
    for (int mt = 0; mt < 4; ++mt)
      af[mt] = *(const s16x8*)(sA + (wy * 64 + mt * 16 + l16) * 32 + quad * 8);
    for (int nt = 0; nt < 4; ++nt)
      bfr[nt] = *(const s16x8*)(sB + (wx * 64 + nt * 16 + l16) * 32 + quad * 8);
    for (int mt = 0; mt < 4; ++mt)
      for (int nt = 0; nt < 4; ++nt)
        acc[mt][nt] = mfma16(af[mt], bfr[nt], acc[mt][nt]);
  }

  for (int mt = 0; mt < 4; ++mt)
    for (int nt = 0; nt < 4; ++nt) {
      int col = n0 + wx * 64 + nt * 16 + l16;
      float bcol = bias[col];
      for (int r = 0; r < 4; ++r) {
        int row = m0 + wy * 64 + mt * 16 + quad * 4 + r;
        float v = acc[mt][nt][r] + bcol;
        if (MODE == 1) {
          v += resid[(size_t)row * N + col];
          ((float*)Cout)[(size_t)row * N + col] = v;
        } else {
          ((unsigned short*)Cout)[(size_t)row * N + col] = f2bf(v);
        }
      }
    }
}

// ---------------- fused flash attention ----------------
// grid: (SEQ/64, B*NHEAD). block: 256 (4 waves). Each wave: 16 q-rows.
__global__ __launch_bounds__(256) void flash_kernel(
    const unsigned short* __restrict__ Qp,
    const unsigned short* __restrict__ Kp,
    const unsigned short* __restrict__ Vp,
    unsigned short* __restrict__ ctx)
{
  __shared__ __align__(16) unsigned short sQ[64 * 64];
  __shared__ __align__(16) unsigned short sK[64 * 64];
  __shared__ __align__(16) unsigned short sVt[64 * 64];   // [dv][key], key-blocks xor-swizzled
  __shared__ __align__(16) unsigned short sP[64 * SPST];

  const int tid = threadIdx.x;
  const int wave = tid >> 6, lane = tid & 63;
  const int quad = lane >> 4, l16 = lane & 15;
  const int q0 = blockIdx.x * 64;
  const int bh = blockIdx.y;
  const int b = bh >> 4, h = bh & 15;
  const size_t base = (size_t)b * SEQ * D_FEAT + (size_t)h * DK;

  // stage Q tile (64 rows x 64 dk)
  for (int i = 0; i < 2; ++i) {
    int c = tid + 256 * i;
    int row = c >> 3, col = (c & 7) * 8;
    *(s16x8*)(sQ + row * 64 + col) =
        *(const s16x8*)(Qp + base + (size_t)(q0 + row) * D_FEAT + col);
  }
  __syncthreads();

  s16x8 aq0 = *(const s16x8*)(sQ + (wave * 16 + l16) * 64 + quad * 8);
  s16x8 aq1 = *(const s16x8*)(sQ + (wave * 16 + l16) * 64 + 32 + quad * 8);

  float m_i[4], l_i[4];
  f32x4 o[4];
  for (int r = 0; r < 4; ++r) { m_i[r] = -INFINITY; l_i[r] = 0.f; }
  for (int nt = 0; nt < 4; ++nt) o[nt] = (f32x4){0.f, 0.f, 0.f, 0.f};

  const float sc = 0.125f * 1.44269504088896f;  // 1/sqrt(64) * log2(e)

  for (int k0 = 0; k0 < SEQ; k0 += 64) {
    __syncthreads();  // prior-iter PV reads done before restaging sK/sVt
    for (int i = 0; i < 2; ++i) {
      int c = tid + 256 * i;
      int row = c >> 3, col = (c & 7) * 8;
      *(s16x8*)(sK + row * 64 + col) =
          *(const s16x8*)(Kp + base + (size_t)(k0 + row) * D_FEAT + col);
    }
    for (int i = 0; i < 2; ++i) {
      int c = tid + 256 * i;
      int key = c >> 3, col = (c & 7) * 8;
      s16x8 vv = *(const s16x8*)(Vp + base + (size_t)(k0 + key) * D_FEAT + col);
      for (int j = 0; j < 8; ++j) {
        int dv = col + j;
        sVt[dv * 64 + ((((key >> 3) ^ (dv >> 3)) & 7) << 3) + (key & 7)] =
            (unsigned short)vv[j];
      }
    }
    __syncthreads();

    // S = (Q K^T) * scale, in exp2 domain
    f32x4 s[4];
    for (int nt = 0; nt < 4; ++nt) {
      s16x8 bk0 = *(const s16x8*)(sK + (nt * 16 + l16) * 64 + quad * 8);
      s16x8 bk1 = *(const s16x8*)(sK + (nt * 16 + l16) * 64 + 32 + quad * 8);
      f32x4 z = (f32x4){0.f, 0.f, 0.f, 0.f};
      z = mfma16(aq0, bk0, z);
      z = mfma16(aq1, bk1, z);
      s[nt] = z * sc;
    }

    // online softmax per q-row (rows quad*4+r, reduce across 16 lanes)
    float p[4][4], alpha[4];
    for (int r = 0; r < 4; ++r) {
      float mx = fmaxf(fmaxf(s[0][r], s[1][r]), fmaxf(s[2][r], s[3][r]));
      for (int off = 1; off < 16; off <<= 1)
        mx = fmaxf(mx, __shfl_xor(mx, off, 64));
      float mn = fmaxf(m_i[r], mx);
      alpha[r] = __builtin_exp2f(m_i[r] - mn);
      m_i[r] = mn;
      float sum = 0.f;
      for (int nt = 0; nt < 4; ++nt) {
        float pv = __builtin_exp2f(s[nt][r] - mn);
        p[nt][r] = pv; sum += pv;
      }
      for (int off = 1; off < 16; off <<= 1)
        sum += __shfl_xor(sum, off, 64);
      l_i[r] = l_i[r] * alpha[r] + sum;
    }

    // rescale O, spill P (C-layout) to LDS for A-operand re-read
    for (int nt = 0; nt < 4; ++nt)
      for (int r = 0; r < 4; ++r) {
        o[nt][r] *= alpha[r];
        sP[(wave * 16 + quad * 4 + r) * SPST + nt * 16 + l16] = f2bf(p[nt][r]);
      }
    // each wave reads only its own sP strip -> wave-synchronous, no barrier needed
    s16x8 ap0 = *(const s16x8*)(sP + (wave * 16 + l16) * SPST + quad * 8);
    s16x8 ap1 = *(const s16x8*)(sP + (wave * 16 + l16) * SPST + 32 + quad * 8);
    for (int nt = 0; nt < 4; ++nt) {
      int dv = nt * 16 + l16;
      int swz = (dv >> 3) & 7;
      s16x8 bv0 = *(const s16x8*)(sVt + dv * 64 + (((quad) ^ swz) << 3));
      s16x8 bv1 = *(const s16x8*)(sVt + dv * 64 + (((4 + quad) ^ swz) << 3));
      o[nt] = mfma16(ap0, bv0, o[nt]);
      o[nt] = mfma16(ap1, bv1, o[nt]);
    }
  }

  for (int nt = 0; nt < 4; ++nt)
    for (int r = 0; r < 4; ++r) {
      float val = o[nt][r] / l_i[r];
      int row = q0 + wave * 16 + quad * 4 + r;
      ctx[base + (size_t)row * D_FEAT + nt * 16 + l16] = f2bf(val);
    }
}

// ---------------- LayerNorm over last dim (1024) ----------------
__global__ __launch_bounds__(256) void ln_kernel(
    const float* __restrict__ x, const float* __restrict__ gamma,
    const float* __restrict__ beta, float* __restrict__ out)
{
  const int row = blockIdx.x, tid = threadIdx.x;
  const int wave = tid >> 6, lane = tid & 63;
  const float* xr = x + (size_t)row * D_FEAT;
  float4 v = ((const float4*)xr)[tid];
  float s  = v.x + v.y + v.z + v.w;
  float ss = v.x * v.x + v.y * v.y + v.z * v.z + v.w * v.w;
  for (int off = 1; off < 64; off <<= 1) {
    s  += __shfl_xor(s,  off, 64);
    ss += __shfl_xor(ss, off, 64);
  }
  __shared__ float red[8];
  if (lane == 0) { red[wave] = s; red[wave + 4] = ss; }
  __syncthreads();
  s  = red[0] + red[1] + red[2] + red[3];
  ss = red[4] + red[5] + red[6] + red[7];
  float mean = s * (1.f / D_FEAT);
  float var  = ss * (1.f / D_FEAT) - mean * mean;
  float rstd = rsqrtf(var + 1e-6f);
  float4 g  = ((const float4*)gamma)[tid];
  float4 bt = ((const float4*)beta)[tid];
  float4 o;
  o.x = (v.x - mean) * rstd * g.x + bt.x;
  o.y = (v.y - mean) * rstd * g.y + bt.y;
  o.z = (v.z - mean) * rstd * g.z + bt.z;
  o.w = (v.w - mean) * rstd * g.w + bt.w;
  ((float4*)(out + (size_t)row * D_FEAT))[tid] = o;
}

extern "C" void kernel_launch(void* const* d_in, const int* in_sizes, int n_in,
                              void* d_out, int out_size, void* d_ws, size_t ws_size,
                              hipStream_t stream) {
  const float* q     = (const float*)d_in[0];
  const float* k     = (const float*)d_in[1];
  const float* v     = (const float*)d_in[2];
  const float* Wq    = (const float*)d_in[3];
  const float* bq    = (const float*)d_in[4];
  const float* Wk    = (const float*)d_in[5];
  const float* bk    = (const float*)d_in[6];
  const float* Wv    = (const float*)d_in[7];
  const float* bv    = (const float*)d_in[8];
  const float* Wo    = (const float*)d_in[9];
  const float* bo    = (const float*)d_in[10];
  const float* gamma = (const float*)d_in[11];
  const float* beta  = (const float*)d_in[12];

  char* w = (char*)d_ws;
  const size_t MB = 1u << 20;
  unsigned short* qb  = (unsigned short*)(w + 0 * MB);
  unsigned short* kb  = (unsigned short*)(w + 8 * MB);
  unsigned short* vb  = (unsigned short*)(w + 16 * MB);
  unsigned short* Wqt = (unsigned short*)(w + 24 * MB);
  unsigned short* Wkt = (unsigned short*)(w + 26 * MB);
  unsigned short* Wvt = (unsigned short*)(w + 28 * MB);
  unsigned short* Wot = (unsigned short*)(w + 30 * MB);
  unsigned short* Qp  = (unsigned short*)(w + 32 * MB);
  unsigned short* Kp  = (unsigned short*)(w + 40 * MB);
  unsigned short* Vp  = (unsigned short*)(w + 48 * MB);
  unsigned short* ctx = (unsigned short*)(w + 56 * MB);
  float*          tmp = (float*)(w + 64 * MB);

  cast_bf16_kernel<<<dim3(4096, 3), 256, 0, stream>>>(q, k, v, qb, kb, vb);
  transpose_cast_kernel<<<dim3(32, 32, 4), dim3(32, 8), 0, stream>>>(
      Wq, Wk, Wv, Wo, Wqt, Wkt, Wvt, Wot);

  gemm_tn<0><<<dim3(8, 32), 256, 0, stream>>>(qb, Wqt, bq, nullptr, Qp, NTOK, D_FEAT, D_FEAT);
  gemm_tn<0><<<dim3(8, 32), 256, 0, stream>>>(kb, Wkt, bk, nullptr, Kp, NTOK, D_FEAT, D_FEAT);
  gemm_tn<0><<<dim3(8, 32), 256, 0, stream>>>(vb, Wvt, bv, nullptr, Vp, NTOK, D_FEAT, D_FEAT);

  flash_kernel<<<dim3(SEQ / 64, 32), 256, 0, stream>>>(Qp, Kp, Vp, ctx);

  gemm_tn<1><<<dim3(8, 32), 256, 0, stream>>>(ctx, Wot, bo, v, tmp, NTOK, D_FEAT, D_FEAT);

  ln_kernel<<<NTOK, 256, 0, stream>>>(tmp, gamma, beta, (float*)d_out);
}

// Round 2
// 296.571 us; speedup vs baseline: 1.3415x; 1.3415x over previous
//
#include <hip/hip_runtime.h>

#define D_FEAT 1024
#define NTOK   4096
#define SEQ    2048
#define NHEAD  16
#define DK     64
#define SPST   72
#define QSCALE 0.1803368801111204f  // 0.125 * log2(e)

typedef float          f32x4 __attribute__((ext_vector_type(4)));
typedef short          s16x8 __attribute__((ext_vector_type(8)));
typedef unsigned short u16x4 __attribute__((ext_vector_type(4)));

__device__ __forceinline__ unsigned short f2bf(float f) {
  union { float f; unsigned int u; } x; x.f = f;
  unsigned int r = x.u + 0x7fffu + ((x.u >> 16) & 1u);
  return (unsigned short)(r >> 16);
}

__device__ __forceinline__ f32x4 mfma16(s16x8 a, s16x8 b, f32x4 c) {
  return __builtin_amdgcn_mfma_f32_16x16x32_bf16(a, b, c, 0, 0, 0);
}

// async global -> LDS, 16B per lane (dest = wave-uniform base + lane*16)
__device__ __forceinline__ void gload16(const void* g, void* l) {
  __builtin_amdgcn_global_load_lds(
      (const __attribute__((address_space(1))) void*)g,
      (__attribute__((address_space(3))) void*)l, 16, 0, 0);
}

// ---------------- cast fp32 -> bf16 for q,k,v ----------------
__global__ __launch_bounds__(256) void cast_bf16_kernel(
    const float* __restrict__ q, const float* __restrict__ k, const float* __restrict__ v,
    unsigned short* __restrict__ qb, unsigned short* __restrict__ kb, unsigned short* __restrict__ vb)
{
  int sel = blockIdx.y;
  const float* src = sel == 0 ? q : (sel == 1 ? k : v);
  unsigned short* dst = sel == 0 ? qb : (sel == 1 ? kb : vb);
  size_t i = ((size_t)blockIdx.x * 256 + threadIdx.x) * 4;
  float4 f = *(const float4*)(src + i);
  u16x4 o; o.x = f2bf(f.x); o.y = f2bf(f.y); o.z = f2bf(f.z); o.w = f2bf(f.w);
  *(u16x4*)(dst + i) = o;
}

// ---------------- transpose + cast weights: W (K x N) fp32 -> Wt (N x K) bf16 ----------------
// z=0,1,2 -> rows z*1024.. of concatenated WT (Wq^T,Wk^T,Wv^T); z=3 -> Wot
__global__ __launch_bounds__(256) void transpose_cast_kernel(
    const float* __restrict__ W0, const float* __restrict__ W1,
    const float* __restrict__ W2, const float* __restrict__ W3,
    unsigned short* __restrict__ WT, unsigned short* __restrict__ Wot)
{
  __shared__ float tile[32][33];
  int z = blockIdx.z;
  const float* W = z == 0 ? W0 : z == 1 ? W1 : z == 2 ? W2 : W3;
  unsigned short* T = (z < 3) ? (WT + (size_t)z * 1024 * 1024) : Wot;
  int tx = threadIdx.x, ty = threadIdx.y;
  int n = blockIdx.x * 32 + tx;
  for (int i = 0; i < 4; ++i) {
    int k = blockIdx.y * 32 + ty + i * 8;
    tile[ty + i * 8][tx] = W[(size_t)k * D_FEAT + n];
  }
  __syncthreads();
  int k = blockIdx.y * 32 + tx;
  for (int i = 0; i < 4; ++i) {
    int n2 = blockIdx.x * 32 + ty + i * 8;
    T[(size_t)n2 * D_FEAT + k] = f2bf(tile[tx][ty + i * 8]);
  }
}

// ---------------- fused QKV projection GEMM ----------------
// C(4096 x 3072) = [qb|kb|vb](4096x1024) * WT(3072x1024)^T, 128x128 tiles.
// n-chunk selects A source, bias, output buffer; Q-proj output pre-scaled.
__global__ __launch_bounds__(256) void gemm_qkv(
    const unsigned short* __restrict__ qb, const unsigned short* __restrict__ kb,
    const unsigned short* __restrict__ vb, const unsigned short* __restrict__ WT,
    const float* __restrict__ bq, const float* __restrict__ bk, const float* __restrict__ bv,
    unsigned short* __restrict__ Qp, unsigned short* __restrict__ Kp, unsigned short* __restrict__ Vp)
{
  __shared__ __align__(16) unsigned short sA[128 * 32];
  __shared__ __align__(16) unsigned short sB[128 * 32];
  const int tid = threadIdx.x;
  const int wave = tid >> 6, lane = tid & 63;
  const int quad = lane >> 4, l16 = lane & 15;
  const int wx = wave & 1, wy = wave >> 1;
  const int n0g = blockIdx.x * 128, m0 = blockIdx.y * 128;
  const int chunk = n0g >> 10, nloc = n0g & 1023;
  const unsigned short* A = chunk == 0 ? qb : chunk == 1 ? kb : vb;
  const float* bias = chunk == 0 ? bq : chunk == 1 ? bk : bv;
  unsigned short* Cp = chunk == 0 ? Qp : chunk == 1 ? Kp : Vp;
  const float scale = chunk == 0 ? QSCALE : 1.0f;

  f32x4 acc[4][4];
  for (int mt = 0; mt < 4; ++mt)
    for (int nt = 0; nt < 4; ++nt) acc[mt][nt] = (f32x4){0.f, 0.f, 0.f, 0.f};

  const int rw = lane >> 2, cl = (lane & 3) * 8;
  for (int k0 = 0; k0 < D_FEAT; k0 += 32) {
    __syncthreads();
    for (int j = 0; j < 2; ++j) {
      int ch = wave * 2 + j;
      gload16(A + (size_t)(m0 + ch * 16 + rw) * D_FEAT + k0 + cl, sA + ch * 512);
      gload16(WT + (size_t)(n0g + ch * 16 + rw) * D_FEAT + k0 + cl, sB + ch * 512);
    }
    __syncthreads();
    s16x8 af[4], bfr[4];
    for (int mt = 0; mt < 4; ++mt)
      af[mt] = *(const s16x8*)(sA + (wy * 64 + mt * 16 + l16) * 32 + quad * 8);
    for (int nt = 0; nt < 4; ++nt)
      bfr[nt] = *(const s16x8*)(sB + (wx * 64 + nt * 16 + l16) * 32 + quad * 8);
    for (int mt = 0; mt < 4; ++mt)
      for (int nt = 0; nt < 4; ++nt)
        acc[mt][nt] = mfma16(af[mt], bfr[nt], acc[mt][nt]);
  }

  for (int mt = 0; mt < 4; ++mt)
    for (int nt = 0; nt < 4; ++nt) {
      int col = nloc + wx * 64 + nt * 16 + l16;
      float bcol = bias[col];
      for (int r = 0; r < 4; ++r) {
        int row = m0 + wy * 64 + mt * 16 + quad * 4 + r;
        Cp[(size_t)row * D_FEAT + col] = f2bf((acc[mt][nt][r] + bcol) * scale);
      }
    }
}

// ---------------- out-projection GEMM + bias + residual (fp32 out) ----------------
__global__ __launch_bounds__(256) void gemm_o(
    const unsigned short* __restrict__ A, const unsigned short* __restrict__ Bt,
    const float* __restrict__ bias, const float* __restrict__ resid,
    float* __restrict__ Cout)
{
  __shared__ __align__(16) unsigned short sA[128 * 32];
  __shared__ __align__(16) unsigned short sB[128 * 32];
  const int tid = threadIdx.x;
  const int wave = tid >> 6, lane = tid & 63;
  const int quad = lane >> 4, l16 = lane & 15;
  const int wx = wave & 1, wy = wave >> 1;
  const int n0 = blockIdx.x * 128, m0 = blockIdx.y * 128;

  f32x4 acc[4][4];
  for (int mt = 0; mt < 4; ++mt)
    for (int nt = 0; nt < 4; ++nt) acc[mt][nt] = (f32x4){0.f, 0.f, 0.f, 0.f};

  const int rw = lane >> 2, cl = (lane & 3) * 8;
  for (int k0 = 0; k0 < D_FEAT; k0 += 32) {
    __syncthreads();
    for (int j = 0; j < 2; ++j) {
      int ch = wave * 2 + j;
      gload16(A + (size_t)(m0 + ch * 16 + rw) * D_FEAT + k0 + cl, sA + ch * 512);
      gload16(Bt + (size_t)(n0 + ch * 16 + rw) * D_FEAT + k0 + cl, sB + ch * 512);
    }
    __syncthreads();
    s16x8 af[4], bfr[4];
    for (int mt = 0; mt < 4; ++mt)
      af[mt] = *(const s16x8*)(sA + (wy * 64 + mt * 16 + l16) * 32 + quad * 8);
    for (int nt = 0; nt < 4; ++nt)
      bfr[nt] = *(const s16x8*)(sB + (wx * 64 + nt * 16 + l16) * 32 + quad * 8);
    for (int mt = 0; mt < 4; ++mt)
      for (int nt = 0; nt < 4; ++nt)
        acc[mt][nt] = mfma16(af[mt], bfr[nt], acc[mt][nt]);
  }

  for (int mt = 0; mt < 4; ++mt)
    for (int nt = 0; nt < 4; ++nt) {
      int col = n0 + wx * 64 + nt * 16 + l16;
      float bcol = bias[col];
      for (int r = 0; r < 4; ++r) {
        int row = m0 + wy * 64 + mt * 16 + quad * 4 + r;
        Cout[(size_t)row * D_FEAT + col] =
            acc[mt][nt][r] + bcol + resid[(size_t)row * D_FEAT + col];
      }
    }
}

// ---------------- V transpose per head: [token][dv] -> Vt[bh][dv][token] ----------------
__global__ __launch_bounds__(256) void vtrans_kernel(
    const unsigned short* __restrict__ Vp, unsigned short* __restrict__ Vt)
{
  __shared__ unsigned short t[64][SPST];
  const int tid = threadIdx.x;
  const int bh = blockIdx.y, b = bh >> 4, h = bh & 15;
  const size_t src = (size_t)b * SEQ * D_FEAT + (size_t)h * DK;
  const int t0 = blockIdx.x * 64;
  for (int i = 0; i < 2; ++i) {
    int c = tid + i * 256;
    int tok = c >> 3, dv = (c & 7) * 8;
    s16x8 v = *(const s16x8*)(Vp + src + (size_t)(t0 + tok) * D_FEAT + dv);
    for (int j = 0; j < 8; ++j) t[dv + j][tok] = (unsigned short)v[j];
  }
  __syncthreads();
  for (int i = 0; i < 2; ++i) {
    int c = tid + i * 256;
    int dv = c >> 3, tk = (c & 7) * 8;
    *(s16x8*)(Vt + ((size_t)bh * 64 + dv) * SEQ + t0 + tk) = *(const s16x8*)(&t[dv][tk]);
  }
}

// ---------------- fused flash attention (S^T formulation) ----------------
// grid: (SEQ/64, B*NHEAD), 4 waves, 16 q-rows per wave.
// QK^T computed transposed (m=key, n=q): lane holds 16 scores of ONE q (=l16)
// -> softmax max needs only 2 cross-quad shuffles; row-sum via MFMA vs ones.
__global__ __launch_bounds__(256) void flash_kernel(
    const unsigned short* __restrict__ Qp,
    const unsigned short* __restrict__ Kp,
    const unsigned short* __restrict__ Vt,
    unsigned short* __restrict__ ctx)
{
  __shared__ __align__(16) unsigned short sQ[64 * 64];
  __shared__ __align__(16) unsigned short sK[64 * 64];
  __shared__ __align__(16) unsigned short sV[64 * 64];   // Vt tile: [dv][key]
  __shared__ __align__(16) unsigned short sP[64 * SPST];

  const int tid = threadIdx.x;
  const int wave = tid >> 6, lane = tid & 63;
  const int quad = lane >> 4, l16 = lane & 15;
  const int q0 = blockIdx.x * 64;
  const int bh = blockIdx.y, b = bh >> 4, h = bh & 15;
  const size_t base = (size_t)b * SEQ * D_FEAT + (size_t)h * DK;
  const unsigned short* vt = Vt + (size_t)bh * 64 * SEQ;

  // stage Q tile (64 x 64)
  for (int i = 0; i < 2; ++i) {
    int c = tid + 256 * i;
    int row = c >> 3, col = (c & 7) * 8;
    *(s16x8*)(sQ + row * 64 + col) =
        *(const s16x8*)(Qp + base + (size_t)(q0 + row) * D_FEAT + col);
  }
  __syncthreads();

  // B-operand Q fragments (hoisted): B[n=q=l16][k=d]
  const s16x8 bq0 = *(const s16x8*)(sQ + (wave * 16 + l16) * 64 + quad * 8);
  const s16x8 bq1 = *(const s16x8*)(sQ + (wave * 16 + l16) * 64 + 32 + quad * 8);

  s16x8 ones;
  for (int j = 0; j < 8; ++j) ones[j] = (short)0x3F80;  // bf16 1.0

  float m_i = -INFINITY;        // per-lane q = l16 of wave strip
  f32x4 l_i = (f32x4){0.f, 0.f, 0.f, 0.f};  // C-row mapping q = quad*4+r
  f32x4 o[4];
  for (int nt = 0; nt < 4; ++nt) o[nt] = (f32x4){0.f, 0.f, 0.f, 0.f};

  const int rw = lane >> 3, cl = (lane & 7) * 8;

  for (int k0 = 0; k0 < SEQ; k0 += 64) {
    __syncthreads();  // prior-iter sK/sV reads done
    for (int j = 0; j < 2; ++j) {
      int ch = wave * 2 + j;
      gload16(Kp + base + (size_t)(k0 + ch * 8 + rw) * D_FEAT + cl, sK + ch * 512);
      gload16(vt + (size_t)(ch * 8 + rw) * SEQ + k0 + cl, sV + ch * 512);
    }
    __syncthreads();

    // S^T = K Q^T (scale pre-folded into Q): rows=key, cols=q
    f32x4 st[4];
    for (int nt = 0; nt < 4; ++nt) {
      s16x8 ak0 = *(const s16x8*)(sK + (nt * 16 + l16) * 64 + quad * 8);
      s16x8 ak1 = *(const s16x8*)(sK + (nt * 16 + l16) * 64 + 32 + quad * 8);
      f32x4 z = (f32x4){0.f, 0.f, 0.f, 0.f};
      z = mfma16(ak0, bq0, z);
      st[nt] = mfma16(ak1, bq1, z);
    }

    // per-lane max over the 16 held scores of q=l16, then cross-quad
    float mx = st[0][0];
    for (int nt = 0; nt < 4; ++nt)
      for (int r = 0; r < 4; ++r) mx = fmaxf(mx, st[nt][r]);
    mx = fmaxf(mx, __shfl_xor(mx, 16, 64));
    mx = fmaxf(mx, __shfl_xor(mx, 32, 64));
    float mn = fmaxf(m_i, mx);
    float alpha = __builtin_exp2f(m_i - mn);
    m_i = mn;

    // P = exp2(S^T - m), packed bf16 (truncate; denominator uses same values)
    for (int nt = 0; nt < 4; ++nt) {
      unsigned int u[4];
      for (int r = 0; r < 4; ++r) {
        union { float f; unsigned int v; } x;
        x.f = __builtin_exp2f(st[nt][r] - mn);
        u[r] = x.v;
      }
      unsigned int w0 = __builtin_amdgcn_perm(u[1], u[0], 0x07060302u);
      unsigned int w1 = __builtin_amdgcn_perm(u[3], u[2], 0x07060302u);
      *(uint2*)(sP + (wave * 16 + l16) * SPST + nt * 16 + quad * 4) =
          make_uint2(w0, w1);
    }

    // alpha into C-row mapping (q = quad*4+r)
    float ar[4];
    for (int r = 0; r < 4; ++r) ar[r] = __shfl(alpha, quad * 4 + r, 64);
    for (int nt = 0; nt < 4; ++nt)
      for (int r = 0; r < 4; ++r) o[nt][r] *= ar[r];
    for (int r = 0; r < 4; ++r) l_i[r] *= ar[r];

    // re-read P as A-operand (same wave wrote it -> wave-ordered, no barrier)
    s16x8 ap0 = *(const s16x8*)(sP + (wave * 16 + l16) * SPST + quad * 8);
    s16x8 ap1 = *(const s16x8*)(sP + (wave * 16 + l16) * SPST + 32 + quad * 8);

    // row sums via MFMA against ones
    f32x4 zs = (f32x4){0.f, 0.f, 0.f, 0.f};
    zs = mfma16(ap0, ones, zs);
    zs = mfma16(ap1, ones, zs);
    for (int r = 0; r < 4; ++r) l_i[r] += zs[r];

    // O += P * V^T : B[n=dv][k=key] from sV
    for (int nt = 0; nt < 4; ++nt) {
      s16x8 bv0 = *(const s16x8*)(sV + (nt * 16 + l16) * 64 + quad * 8);
      s16x8 bv1 = *(const s16x8*)(sV + (nt * 16 + l16) * 64 + 32 + quad * 8);
      o[nt] = mfma16(ap0, bv0, o[nt]);
      o[nt] = mfma16(ap1, bv1, o[nt]);
    }
  }

  for (int nt = 0; nt < 4; ++nt)
    for (int r = 0; r < 4; ++r) {
      float val = o[nt][r] / l_i[r];
      int row = q0 + wave * 16 + quad * 4 + r;
      ctx[base + (size_t)row * D_FEAT + nt * 16 + l16] = f2bf(val);
    }
}

// ---------------- LayerNorm over last dim (1024) ----------------
__global__ __launch_bounds__(256) void ln_kernel(
    const float* __restrict__ x, const float* __restrict__ gamma,
    const float* __restrict__ beta, float* __restrict__ out)
{
  const int row = blockIdx.x, tid = threadIdx.x;
  const int wave = tid >> 6, lane = tid & 63;
  const float* xr = x + (size_t)row * D_FEAT;
  float4 v = ((const float4*)xr)[tid];
  float s  = v.x + v.y + v.z + v.w;
  float ss = v.x * v.x + v.y * v.y + v.z * v.z + v.w * v.w;
  for (int off = 1; off < 64; off <<= 1) {
    s  += __shfl_xor(s,  off, 64);
    ss += __shfl_xor(ss, off, 64);
  }
  __shared__ float red[8];
  if (lane == 0) { red[wave] = s; red[wave + 4] = ss; }
  __syncthreads();
  s  = red[0] + red[1] + red[2] + red[3];
  ss = red[4] + red[5] + red[6] + red[7];
  float mean = s * (1.f / D_FEAT);
  float var  = ss * (1.f / D_FEAT) - mean * mean;
  float rstd = rsqrtf(var + 1e-6f);
  float4 g  = ((const float4*)gamma)[tid];
  float4 bt = ((const float4*)beta)[tid];
  float4 o;
  o.x = (v.x - mean) * rstd * g.x + bt.x;
  o.y = (v.y - mean) * rstd * g.y + bt.y;
  o.z = (v.z - mean) * rstd * g.z + bt.z;
  o.w = (v.w - mean) * rstd * g.w + bt.w;
  ((float4*)(out + (size_t)row * D_FEAT))[tid] = o;
}

extern "C" void kernel_launch(void* const* d_in, const int* in_sizes, int n_in,
                              void* d_out, int out_size, void* d_ws, size_t ws_size,
                              hipStream_t stream) {
  const float* q     = (const float*)d_in[0];
  const float* k     = (const float*)d_in[1];
  const float* v     = (const float*)d_in[2];
  const float* Wq    = (const float*)d_in[3];
  const float* bq    = (const float*)d_in[4];
  const float* Wk    = (const float*)d_in[5];
  const float* bk    = (const float*)d_in[6];
  const float* Wv    = (const float*)d_in[7];
  const float* bv    = (const float*)d_in[8];
  const float* Wo    = (const float*)d_in[9];
  const float* bo    = (const float*)d_in[10];
  const float* gamma = (const float*)d_in[11];
  const float* beta  = (const float*)d_in[12];

  char* w = (char*)d_ws;
  const size_t MB = 1u << 20;
  unsigned short* qb  = (unsigned short*)(w + 0 * MB);   // dead after gemm_qkv
  unsigned short* kb  = (unsigned short*)(w + 8 * MB);
  unsigned short* vb  = (unsigned short*)(w + 16 * MB);
  unsigned short* WT  = (unsigned short*)(w + 24 * MB);  // 6 MB: Wq^T|Wk^T|Wv^T
  unsigned short* Wot = (unsigned short*)(w + 30 * MB);
  unsigned short* Qp  = (unsigned short*)(w + 32 * MB);
  unsigned short* Kp  = (unsigned short*)(w + 40 * MB);
  unsigned short* Vp  = (unsigned short*)(w + 48 * MB);
  unsigned short* ctx = (unsigned short*)(w + 56 * MB);
  float*          tmp = (float*)(w + 64 * MB);           // 16 MB
  unsigned short* Vt  = (unsigned short*)(w + 0 * MB);   // aliases qb (dead by then)

  cast_bf16_kernel<<<dim3(4096, 3), 256, 0, stream>>>(q, k, v, qb, kb, vb);
  transpose_cast_kernel<<<dim3(32, 32, 4), dim3(32, 8), 0, stream>>>(
      Wq, Wk, Wv, Wo, WT, Wot);

  gemm_qkv<<<dim3(24, 32), 256, 0, stream>>>(qb, kb, vb, WT, bq, bk, bv, Qp, Kp, Vp);

  vtrans_kernel<<<dim3(SEQ / 64, 32), 256, 0, stream>>>(Vp, Vt);

  flash_kernel<<<dim3(SEQ / 64, 32), 256, 0, stream>>>(Qp, Kp, Vt, ctx);

  gemm_o<<<dim3(8, 32), 256, 0, stream>>>(ctx, Wot, bo, v, tmp);

  ln_kernel<<<NTOK, 256, 0, stream>>>(tmp, gamma, beta, (float*)d_out);
}

// Round 3
// 280.479 us; speedup vs baseline: 1.4184x; 1.0574x over previous
//
#include <hip/hip_runtime.h>

#define D_FEAT 1024
#define NTOK   4096
#define SEQ    2048
#define NHEAD  16
#define DK     64
#define SPST   72
#define QSCALE 0.1803368801111204f  // 0.125 * log2(e)

typedef float          f32x4 __attribute__((ext_vector_type(4)));
typedef short          s16x8 __attribute__((ext_vector_type(8)));
typedef unsigned short u16x4 __attribute__((ext_vector_type(4)));

__device__ __forceinline__ unsigned short f2bf(float f) {
  union { float f; unsigned int u; } x; x.f = f;
  unsigned int r = x.u + 0x7fffu + ((x.u >> 16) & 1u);
  return (unsigned short)(r >> 16);
}

__device__ __forceinline__ f32x4 mfma16(s16x8 a, s16x8 b, f32x4 c) {
  return __builtin_amdgcn_mfma_f32_16x16x32_bf16(a, b, c, 0, 0, 0);
}

// async global -> LDS, 16B per lane (dest = wave-uniform base + lane*16)
__device__ __forceinline__ void gload16(const void* g, void* l) {
  __builtin_amdgcn_global_load_lds(
      (const __attribute__((address_space(1))) void*)g,
      (__attribute__((address_space(3))) void*)l, 16, 0, 0);
}

// ---------------- cast fp32 -> bf16 for q,k,v ----------------
__global__ __launch_bounds__(256) void cast_bf16_kernel(
    const float* __restrict__ q, const float* __restrict__ k, const float* __restrict__ v,
    unsigned short* __restrict__ qb, unsigned short* __restrict__ kb, unsigned short* __restrict__ vb)
{
  int sel = blockIdx.y;
  const float* src = sel == 0 ? q : (sel == 1 ? k : v);
  unsigned short* dst = sel == 0 ? qb : (sel == 1 ? kb : vb);
  size_t i = ((size_t)blockIdx.x * 256 + threadIdx.x) * 4;
  float4 f = *(const float4*)(src + i);
  u16x4 o; o.x = f2bf(f.x); o.y = f2bf(f.y); o.z = f2bf(f.z); o.w = f2bf(f.w);
  *(u16x4*)(dst + i) = o;
}

// ---------------- transpose + cast weights: W (K x N) fp32 -> Wt (N x K) bf16 ----------------
// z=0,1,2 -> rows z*1024.. of concatenated WT (Wq^T,Wk^T,Wv^T); z=3 -> Wot
__global__ __launch_bounds__(256) void transpose_cast_kernel(
    const float* __restrict__ W0, const float* __restrict__ W1,
    const float* __restrict__ W2, const float* __restrict__ W3,
    unsigned short* __restrict__ WT, unsigned short* __restrict__ Wot)
{
  __shared__ float tile[32][33];
  int z = blockIdx.z;
  const float* W = z == 0 ? W0 : z == 1 ? W1 : z == 2 ? W2 : W3;
  unsigned short* T = (z < 3) ? (WT + (size_t)z * 1024 * 1024) : Wot;
  int tx = threadIdx.x, ty = threadIdx.y;
  int n = blockIdx.x * 32 + tx;
  for (int i = 0; i < 4; ++i) {
    int k = blockIdx.y * 32 + ty + i * 8;
    tile[ty + i * 8][tx] = W[(size_t)k * D_FEAT + n];
  }
  __syncthreads();
  int k = blockIdx.y * 32 + tx;
  for (int i = 0; i < 4; ++i) {
    int n2 = blockIdx.x * 32 + ty + i * 8;
    T[(size_t)n2 * D_FEAT + k] = f2bf(tile[tx][ty + i * 8]);
  }
}

// ---------------- fused QKV projection GEMM ----------------
// blocks x: 0-7 = Q proj (pre-scaled), 8-15 = K proj, 16-23 = V proj computed
// TRANSPOSED (M=features, N=tokens) writing Vt[bh][dv][tok] directly.
// LDS chunk-swizzled: chunk c of row r stored at c ^ ((r>>1)&3).
__global__ __launch_bounds__(256) void gemm_qkv(
    const unsigned short* __restrict__ qb, const unsigned short* __restrict__ kb,
    const unsigned short* __restrict__ vb, const unsigned short* __restrict__ WT,
    const float* __restrict__ bq, const float* __restrict__ bk, const float* __restrict__ bv,
    unsigned short* __restrict__ Qp, unsigned short* __restrict__ Kp, unsigned short* __restrict__ Vt)
{
  __shared__ __align__(16) unsigned short sA[128 * 32];
  __shared__ __align__(16) unsigned short sB[128 * 32];
  const int tid = threadIdx.x;
  const int wave = tid >> 6, lane = tid & 63;
  const int quad = lane >> 4, l16 = lane & 15;
  const int wx = wave & 1, wy = wave >> 1;
  const int bx = blockIdx.x;
  const int chunk = bx >> 3;

  const unsigned short* rA;
  const unsigned short* rB;
  int m0, n0;
  if (chunk < 2) {
    m0 = blockIdx.y * 128; n0 = (bx & 7) * 128;
    rA = (chunk ? kb : qb) + (size_t)m0 * D_FEAT;
    rB = WT + (size_t)(chunk * 1024 + n0) * D_FEAT;
  } else {
    m0 = (bx & 7) * 128; n0 = blockIdx.y * 128;
    rA = WT + (size_t)(2048 + m0) * D_FEAT;
    rB = vb + (size_t)n0 * D_FEAT;
  }

  f32x4 acc[4][4];
  for (int mt = 0; mt < 4; ++mt)
    for (int nt = 0; nt < 4; ++nt) acc[mt][nt] = (f32x4){0.f, 0.f, 0.f, 0.f};

  const int rw = lane >> 2;
  const int cl = (((lane & 3) ^ ((lane >> 3) & 3))) * 8;   // swizzled global chunk
  const int g0 = (quad ^ ((l16 >> 1) & 3)) * 8;            // swizzled frag chunk

  for (int k0 = 0; k0 < D_FEAT; k0 += 32) {
    __syncthreads();
    for (int j = 0; j < 2; ++j) {
      int ch = wave * 2 + j;
      gload16(rA + (size_t)(ch * 16 + rw) * D_FEAT + k0 + cl, sA + ch * 512);
      gload16(rB + (size_t)(ch * 16 + rw) * D_FEAT + k0 + cl, sB + ch * 512);
    }
    __syncthreads();
    s16x8 af[4], bfr[4];
    for (int mt = 0; mt < 4; ++mt)
      af[mt] = *(const s16x8*)(sA + (wy * 64 + mt * 16 + l16) * 32 + g0);
    for (int nt = 0; nt < 4; ++nt)
      bfr[nt] = *(const s16x8*)(sB + (wx * 64 + nt * 16 + l16) * 32 + g0);
    for (int mt = 0; mt < 4; ++mt)
      for (int nt = 0; nt < 4; ++nt)
        acc[mt][nt] = mfma16(af[mt], bfr[nt], acc[mt][nt]);
  }

  if (chunk < 2) {
    const float* bias = chunk ? bk : bq;
    unsigned short* Cp = chunk ? Kp : Qp;
    const float scale = chunk == 0 ? QSCALE : 1.0f;
    for (int mt = 0; mt < 4; ++mt)
      for (int nt = 0; nt < 4; ++nt) {
        int col = n0 + wx * 64 + nt * 16 + l16;
        float bcol = bias[col];
        for (int r = 0; r < 4; ++r) {
          int row = m0 + wy * 64 + mt * 16 + quad * 4 + r;
          Cp[(size_t)row * D_FEAT + col] = f2bf((acc[mt][nt][r] + bcol) * scale);
        }
      }
  } else {
    for (int mt = 0; mt < 4; ++mt) {
      float bfeat[4];
      for (int r = 0; r < 4; ++r)
        bfeat[r] = bv[m0 + wy * 64 + mt * 16 + quad * 4 + r];
      for (int nt = 0; nt < 4; ++nt) {
        int n = n0 + wx * 64 + nt * 16 + l16;          // token (global)
        int b = n >> 11, tok = n & 2047;
        for (int r = 0; r < 4; ++r) {
          int f = m0 + wy * 64 + mt * 16 + quad * 4 + r;  // v-feature
          int h = f >> 6, dv = f & 63;
          Vt[(((size_t)(b * 16 + h) * 64 + dv) * SEQ) + tok] =
              f2bf(acc[mt][nt][r] + bfeat[r]);
        }
      }
    }
  }
}

// ---------------- out-projection GEMM + bias + residual (fp32 out) ----------------
__global__ __launch_bounds__(256) void gemm_o(
    const unsigned short* __restrict__ A, const unsigned short* __restrict__ Bt,
    const float* __restrict__ bias, const float* __restrict__ resid,
    float* __restrict__ Cout)
{
  __shared__ __align__(16) unsigned short sA[128 * 32];
  __shared__ __align__(16) unsigned short sB[128 * 32];
  const int tid = threadIdx.x;
  const int wave = tid >> 6, lane = tid & 63;
  const int quad = lane >> 4, l16 = lane & 15;
  const int wx = wave & 1, wy = wave >> 1;
  const int n0 = blockIdx.x * 128, m0 = blockIdx.y * 128;

  f32x4 acc[4][4];
  for (int mt = 0; mt < 4; ++mt)
    for (int nt = 0; nt < 4; ++nt) acc[mt][nt] = (f32x4){0.f, 0.f, 0.f, 0.f};

  const int rw = lane >> 2;
  const int cl = (((lane & 3) ^ ((lane >> 3) & 3))) * 8;
  const int g0 = (quad ^ ((l16 >> 1) & 3)) * 8;

  for (int k0 = 0; k0 < D_FEAT; k0 += 32) {
    __syncthreads();
    for (int j = 0; j < 2; ++j) {
      int ch = wave * 2 + j;
      gload16(A + (size_t)(m0 + ch * 16 + rw) * D_FEAT + k0 + cl, sA + ch * 512);
      gload16(Bt + (size_t)(n0 + ch * 16 + rw) * D_FEAT + k0 + cl, sB + ch * 512);
    }
    __syncthreads();
    s16x8 af[4], bfr[4];
    for (int mt = 0; mt < 4; ++mt)
      af[mt] = *(const s16x8*)(sA + (wy * 64 + mt * 16 + l16) * 32 + g0);
    for (int nt = 0; nt < 4; ++nt)
      bfr[nt] = *(const s16x8*)(sB + (wx * 64 + nt * 16 + l16) * 32 + g0);
    for (int mt = 0; mt < 4; ++mt)
      for (int nt = 0; nt < 4; ++nt)
        acc[mt][nt] = mfma16(af[mt], bfr[nt], acc[mt][nt]);
  }

  for (int mt = 0; mt < 4; ++mt)
    for (int nt = 0; nt < 4; ++nt) {
      int col = n0 + wx * 64 + nt * 16 + l16;
      float bcol = bias[col];
      for (int r = 0; r < 4; ++r) {
        int row = m0 + wy * 64 + mt * 16 + quad * 4 + r;
        Cout[(size_t)row * D_FEAT + col] =
            acc[mt][nt][r] + bcol + resid[(size_t)row * D_FEAT + col];
      }
    }
}

// ---------------- fused flash attention (S^T formulation, swizzled LDS) ----------------
// grid: (SEQ/64, B*NHEAD), 4 waves, 16 q-rows per wave, 4 blocks/CU.
// LDS tiles 64x64: chunk c of row r stored at c ^ (r&7)  -> 2-way (free) frag reads.
__global__ __launch_bounds__(256, 4) void flash_kernel(
    const unsigned short* __restrict__ Qp,
    const unsigned short* __restrict__ Kp,
    const unsigned short* __restrict__ Vt,
    unsigned short* __restrict__ ctx)
{
  __shared__ __align__(16) unsigned short sQ[64 * 64];
  __shared__ __align__(16) unsigned short sK[64 * 64];
  __shared__ __align__(16) unsigned short sV[64 * 64];   // Vt tile: [dv][key]
  __shared__ __align__(16) unsigned short sP[64 * SPST];

  const int tid = threadIdx.x;
  const int wave = tid >> 6, lane = tid & 63;
  const int quad = lane >> 4, l16 = lane & 15;
  const int q0 = blockIdx.x * 64;
  const int bh = blockIdx.y, b = bh >> 4, h = bh & 15;
  const size_t base = (size_t)b * SEQ * D_FEAT + (size_t)h * DK;
  const unsigned short* vt = Vt + (size_t)bh * 64 * SEQ;

  // stage Q tile (64 x 64), swizzled
  for (int i = 0; i < 2; ++i) {
    int c = tid + 256 * i;
    int row = c >> 3, csw = ((c & 7) ^ (row & 7)) * 8;
    *(s16x8*)(sQ + row * 64 + csw) =
        *(const s16x8*)(Qp + base + (size_t)(q0 + row) * D_FEAT + (c & 7) * 8);
  }
  __syncthreads();

  const int sw = l16 & 7;
  const int c0 = (quad ^ sw) * 8;          // swizzled chunk for logical cols quad*8
  const int c1 = ((quad + 4) ^ sw) * 8;    // swizzled chunk for logical cols 32+quad*8

  // B-operand Q fragments (hoisted): B[n=q=l16][k=d]
  const s16x8 bq0 = *(const s16x8*)(sQ + (wave * 16 + l16) * 64 + c0);
  const s16x8 bq1 = *(const s16x8*)(sQ + (wave * 16 + l16) * 64 + c1);

  s16x8 ones;
  for (int j = 0; j < 8; ++j) ones[j] = (short)0x3F80;  // bf16 1.0

  float m_i = -INFINITY;                    // per-lane q = l16 of wave strip
  f32x4 l_i = (f32x4){0.f, 0.f, 0.f, 0.f};  // C-row mapping q = quad*4+r
  f32x4 o[4];
  for (int nt = 0; nt < 4; ++nt) o[nt] = (f32x4){0.f, 0.f, 0.f, 0.f};

  const int rw = lane >> 3;
  const int cls = ((lane & 7) ^ (lane >> 3)) * 8;   // swizzled global source chunk

  for (int k0 = 0; k0 < SEQ; k0 += 64) {
    __syncthreads();  // prior-iter sK/sV reads done
    for (int j = 0; j < 2; ++j) {
      int ch = wave * 2 + j;
      gload16(Kp + base + (size_t)(k0 + ch * 8 + rw) * D_FEAT + cls, sK + ch * 512);
      gload16(vt + (size_t)(ch * 8 + rw) * SEQ + k0 + cls, sV + ch * 512);
    }
    __syncthreads();

    // S^T = K Q^T (scale pre-folded into Q): rows=key, cols=q
    f32x4 st[4];
    for (int nt = 0; nt < 4; ++nt) {
      s16x8 ak0 = *(const s16x8*)(sK + (nt * 16 + l16) * 64 + c0);
      s16x8 ak1 = *(const s16x8*)(sK + (nt * 16 + l16) * 64 + c1);
      f32x4 z = (f32x4){0.f, 0.f, 0.f, 0.f};
      z = mfma16(ak0, bq0, z);
      st[nt] = mfma16(ak1, bq1, z);
    }

    // per-lane max over the 16 held scores of q=l16, then cross-quad
    float mx = st[0][0];
    for (int nt = 0; nt < 4; ++nt)
      for (int r = 0; r < 4; ++r) mx = fmaxf(mx, st[nt][r]);
    mx = fmaxf(mx, __shfl_xor(mx, 16, 64));
    mx = fmaxf(mx, __shfl_xor(mx, 32, 64));
    float mn = fmaxf(m_i, mx);
    float alpha = __builtin_exp2f(m_i - mn);
    m_i = mn;

    // P = exp2(S^T - m), packed bf16 (truncate; denominator uses same values)
    for (int nt = 0; nt < 4; ++nt) {
      unsigned int u[4];
      for (int r = 0; r < 4; ++r) {
        union { float f; unsigned int v; } x;
        x.f = __builtin_exp2f(st[nt][r] - mn);
        u[r] = x.v;
      }
      unsigned int w0 = __builtin_amdgcn_perm(u[1], u[0], 0x07060302u);
      unsigned int w1 = __builtin_amdgcn_perm(u[3], u[2], 0x07060302u);
      *(uint2*)(sP + (wave * 16 + l16) * SPST + nt * 16 + quad * 4) =
          make_uint2(w0, w1);
    }

    // alpha into C-row mapping (q = quad*4+r)
    float ar[4];
    for (int r = 0; r < 4; ++r) ar[r] = __shfl(alpha, quad * 4 + r, 64);
    for (int nt = 0; nt < 4; ++nt)
      for (int r = 0; r < 4; ++r) o[nt][r] *= ar[r];
    for (int r = 0; r < 4; ++r) l_i[r] *= ar[r];

    // re-read P as A-operand (same wave wrote it -> wave-ordered, no barrier)
    s16x8 ap0 = *(const s16x8*)(sP + (wave * 16 + l16) * SPST + quad * 8);
    s16x8 ap1 = *(const s16x8*)(sP + (wave * 16 + l16) * SPST + 32 + quad * 8);

    // row sums via MFMA against ones
    f32x4 zs = (f32x4){0.f, 0.f, 0.f, 0.f};
    zs = mfma16(ap0, ones, zs);
    zs = mfma16(ap1, ones, zs);
    for (int r = 0; r < 4; ++r) l_i[r] += zs[r];

    // O += P * V^T : B[n=dv][k=key] from sV
    for (int nt = 0; nt < 4; ++nt) {
      s16x8 bv0 = *(const s16x8*)(sV + (nt * 16 + l16) * 64 + c0);
      s16x8 bv1 = *(const s16x8*)(sV + (nt * 16 + l16) * 64 + c1);
      o[nt] = mfma16(ap0, bv0, o[nt]);
      o[nt] = mfma16(ap1, bv1, o[nt]);
    }
  }

  float inv[4];
  for (int r = 0; r < 4; ++r) inv[r] = __builtin_amdgcn_rcpf(l_i[r]);
  for (int nt = 0; nt < 4; ++nt)
    for (int r = 0; r < 4; ++r) {
      int row = q0 + wave * 16 + quad * 4 + r;
      ctx[base + (size_t)row * D_FEAT + nt * 16 + l16] = f2bf(o[nt][r] * inv[r]);
    }
}

// ---------------- LayerNorm over last dim (1024) ----------------
__global__ __launch_bounds__(256) void ln_kernel(
    const float* __restrict__ x, const float* __restrict__ gamma,
    const float* __restrict__ beta, float* __restrict__ out)
{
  const int row = blockIdx.x, tid = threadIdx.x;
  const int wave = tid >> 6, lane = tid & 63;
  const float* xr = x + (size_t)row * D_FEAT;
  float4 v = ((const float4*)xr)[tid];
  float s  = v.x + v.y + v.z + v.w;
  float ss = v.x * v.x + v.y * v.y + v.z * v.z + v.w * v.w;
  for (int off = 1; off < 64; off <<= 1) {
    s  += __shfl_xor(s,  off, 64);
    ss += __shfl_xor(ss, off, 64);
  }
  __shared__ float red[8];
  if (lane == 0) { red[wave] = s; red[wave + 4] = ss; }
  __syncthreads();
  s  = red[0] + red[1] + red[2] + red[3];
  ss = red[4] + red[5] + red[6] + red[7];
  float mean = s * (1.f / D_FEAT);
  float var  = ss * (1.f / D_FEAT) - mean * mean;
  float rstd = rsqrtf(var + 1e-6f);
  float4 g  = ((const float4*)gamma)[tid];
  float4 bt = ((const float4*)beta)[tid];
  float4 o;
  o.x = (v.x - mean) * rstd * g.x + bt.x;
  o.y = (v.y - mean) * rstd * g.y + bt.y;
  o.z = (v.z - mean) * rstd * g.z + bt.z;
  o.w = (v.w - mean) * rstd * g.w + bt.w;
  ((float4*)(out + (size_t)row * D_FEAT))[tid] = o;
}

extern "C" void kernel_launch(void* const* d_in, const int* in_sizes, int n_in,
                              void* d_out, int out_size, void* d_ws, size_t ws_size,
                              hipStream_t stream) {
  const float* q     = (const float*)d_in[0];
  const float* k     = (const float*)d_in[1];
  const float* v     = (const float*)d_in[2];
  const float* Wq    = (const float*)d_in[3];
  const float* bq    = (const float*)d_in[4];
  const float* Wk    = (const float*)d_in[5];
  const float* bk    = (const float*)d_in[6];
  const float* Wv    = (const float*)d_in[7];
  const float* bv    = (const float*)d_in[8];
  const float* Wo    = (const float*)d_in[9];
  const float* bo    = (const float*)d_in[10];
  const float* gamma = (const float*)d_in[11];
  const float* beta  = (const float*)d_in[12];

  char* w = (char*)d_ws;
  const size_t MB = 1u << 20;
  unsigned short* qb  = (unsigned short*)(w + 0 * MB);
  unsigned short* kb  = (unsigned short*)(w + 8 * MB);
  unsigned short* vb  = (unsigned short*)(w + 16 * MB);
  unsigned short* WT  = (unsigned short*)(w + 24 * MB);  // 6 MB: Wq^T|Wk^T|Wv^T
  unsigned short* Wot = (unsigned short*)(w + 30 * MB);
  unsigned short* Qp  = (unsigned short*)(w + 32 * MB);
  unsigned short* Kp  = (unsigned short*)(w + 40 * MB);
  unsigned short* Vt  = (unsigned short*)(w + 48 * MB);  // [bh][dv][tok] 8 MB
  unsigned short* ctx = (unsigned short*)(w + 56 * MB);
  float*          tmp = (float*)(w + 64 * MB);           // 16 MB

  cast_bf16_kernel<<<dim3(4096, 3), 256, 0, stream>>>(q, k, v, qb, kb, vb);
  transpose_cast_kernel<<<dim3(32, 32, 4), dim3(32, 8), 0, stream>>>(
      Wq, Wk, Wv, Wo, WT, Wot);

  gemm_qkv<<<dim3(24, 32), 256, 0, stream>>>(qb, kb, vb, WT, bq, bk, bv, Qp, Kp, Vt);

  flash_kernel<<<dim3(SEQ / 64, 32), 256, 0, stream>>>(Qp, Kp, Vt, ctx);

  gemm_o<<<dim3(8, 32), 256, 0, stream>>>(ctx, Wot, bo, v, tmp);

  ln_kernel<<<NTOK, 256, 0, stream>>>(tmp, gamma, beta, (float*)d_out);
}

// Round 4
// 278.439 us; speedup vs baseline: 1.4288x; 1.0073x over previous
//
#include <hip/hip_runtime.h>

#define D_FEAT 1024
#define NTOK   4096
#define SEQ    2048
#define NHEAD  16
#define DK     64
#define QSCALE 0.1803368801111204f  // 0.125 * log2(e)

typedef float          f32x4  __attribute__((ext_vector_type(4)));
typedef float          f32x16 __attribute__((ext_vector_type(16)));
typedef short          s16x8  __attribute__((ext_vector_type(8)));
typedef unsigned short u16x4  __attribute__((ext_vector_type(4)));

__device__ __forceinline__ unsigned short f2bf(float f) {
  union { float f; unsigned int u; } x; x.f = f;
  unsigned int r = x.u + 0x7fffu + ((x.u >> 16) & 1u);
  return (unsigned short)(r >> 16);
}

__device__ __forceinline__ f32x4 mfma16(s16x8 a, s16x8 b, f32x4 c) {
  return __builtin_amdgcn_mfma_f32_16x16x32_bf16(a, b, c, 0, 0, 0);
}
__device__ __forceinline__ f32x16 mfma32(s16x8 a, s16x8 b, f32x16 c) {
  return __builtin_amdgcn_mfma_f32_32x32x16_bf16(a, b, c, 0, 0, 0);
}

// async global -> LDS, 16B per lane (dest = wave-uniform base + lane*16)
__device__ __forceinline__ void gload16(const void* g, void* l) {
  __builtin_amdgcn_global_load_lds(
      (const __attribute__((address_space(1))) void*)g,
      (__attribute__((address_space(3))) void*)l, 16, 0, 0);
}

// ---------------- cast fp32 -> bf16 for q,k,v ----------------
__global__ __launch_bounds__(256) void cast_bf16_kernel(
    const float* __restrict__ q, const float* __restrict__ k, const float* __restrict__ v,
    unsigned short* __restrict__ qb, unsigned short* __restrict__ kb, unsigned short* __restrict__ vb)
{
  int sel = blockIdx.y;
  const float* src = sel == 0 ? q : (sel == 1 ? k : v);
  unsigned short* dst = sel == 0 ? qb : (sel == 1 ? kb : vb);
  size_t i = ((size_t)blockIdx.x * 256 + threadIdx.x) * 4;
  float4 f = *(const float4*)(src + i);
  u16x4 o; o.x = f2bf(f.x); o.y = f2bf(f.y); o.z = f2bf(f.z); o.w = f2bf(f.w);
  *(u16x4*)(dst + i) = o;
}

// ---------------- transpose + cast weights ----------------
__global__ __launch_bounds__(256) void transpose_cast_kernel(
    const float* __restrict__ W0, const float* __restrict__ W1,
    const float* __restrict__ W2, const float* __restrict__ W3,
    unsigned short* __restrict__ WT, unsigned short* __restrict__ Wot)
{
  __shared__ float tile[32][33];
  int z = blockIdx.z;
  const float* W = z == 0 ? W0 : z == 1 ? W1 : z == 2 ? W2 : W3;
  unsigned short* T = (z < 3) ? (WT + (size_t)z * 1024 * 1024) : Wot;
  int tx = threadIdx.x, ty = threadIdx.y;
  int n = blockIdx.x * 32 + tx;
  for (int i = 0; i < 4; ++i) {
    int k = blockIdx.y * 32 + ty + i * 8;
    tile[ty + i * 8][tx] = W[(size_t)k * D_FEAT + n];
  }
  __syncthreads();
  int k = blockIdx.y * 32 + tx;
  for (int i = 0; i < 4; ++i) {
    int n2 = blockIdx.x * 32 + ty + i * 8;
    T[(size_t)n2 * D_FEAT + k] = f2bf(tile[tx][ty + i * 8]);
  }
}

// ---------------- fused QKV projection GEMM ----------------
__global__ __launch_bounds__(256) void gemm_qkv(
    const unsigned short* __restrict__ qb, const unsigned short* __restrict__ kb,
    const unsigned short* __restrict__ vb, const unsigned short* __restrict__ WT,
    const float* __restrict__ bq, const float* __restrict__ bk, const float* __restrict__ bv,
    unsigned short* __restrict__ Qp, unsigned short* __restrict__ Kp, unsigned short* __restrict__ Vt)
{
  __shared__ __align__(16) unsigned short sA[128 * 32];
  __shared__ __align__(16) unsigned short sB[128 * 32];
  const int tid = threadIdx.x;
  const int wave = tid >> 6, lane = tid & 63;
  const int quad = lane >> 4, l16 = lane & 15;
  const int wx = wave & 1, wy = wave >> 1;
  const int bx = blockIdx.x;
  const int chunk = bx >> 3;

  const unsigned short* rA;
  const unsigned short* rB;
  int m0, n0;
  if (chunk < 2) {
    m0 = blockIdx.y * 128; n0 = (bx & 7) * 128;
    rA = (chunk ? kb : qb) + (size_t)m0 * D_FEAT;
    rB = WT + (size_t)(chunk * 1024 + n0) * D_FEAT;
  } else {
    m0 = (bx & 7) * 128; n0 = blockIdx.y * 128;
    rA = WT + (size_t)(2048 + m0) * D_FEAT;
    rB = vb + (size_t)n0 * D_FEAT;
  }

  f32x4 acc[4][4];
  for (int mt = 0; mt < 4; ++mt)
    for (int nt = 0; nt < 4; ++nt) acc[mt][nt] = (f32x4){0.f, 0.f, 0.f, 0.f};

  const int rw = lane >> 2;
  const int cl = (((lane & 3) ^ ((lane >> 3) & 3))) * 8;
  const int g0 = (quad ^ ((l16 >> 1) & 3)) * 8;

  for (int k0 = 0; k0 < D_FEAT; k0 += 32) {
    __syncthreads();
    for (int j = 0; j < 2; ++j) {
      int ch = wave * 2 + j;
      gload16(rA + (size_t)(ch * 16 + rw) * D_FEAT + k0 + cl, sA + ch * 512);
      gload16(rB + (size_t)(ch * 16 + rw) * D_FEAT + k0 + cl, sB + ch * 512);
    }
    __syncthreads();
    s16x8 af[4], bfr[4];
    for (int mt = 0; mt < 4; ++mt)
      af[mt] = *(const s16x8*)(sA + (wy * 64 + mt * 16 + l16) * 32 + g0);
    for (int nt = 0; nt < 4; ++nt)
      bfr[nt] = *(const s16x8*)(sB + (wx * 64 + nt * 16 + l16) * 32 + g0);
    for (int mt = 0; mt < 4; ++mt)
      for (int nt = 0; nt < 4; ++nt)
        acc[mt][nt] = mfma16(af[mt], bfr[nt], acc[mt][nt]);
  }

  if (chunk < 2) {
    const float* bias = chunk ? bk : bq;
    unsigned short* Cp = chunk ? Kp : Qp;
    const float scale = chunk == 0 ? QSCALE : 1.0f;
    for (int mt = 0; mt < 4; ++mt)
      for (int nt = 0; nt < 4; ++nt) {
        int col = n0 + wx * 64 + nt * 16 + l16;
        float bcol = bias[col];
        for (int r = 0; r < 4; ++r) {
          int row = m0 + wy * 64 + mt * 16 + quad * 4 + r;
          Cp[(size_t)row * D_FEAT + col] = f2bf((acc[mt][nt][r] + bcol) * scale);
        }
      }
  } else {
    for (int mt = 0; mt < 4; ++mt) {
      float bfeat[4];
      for (int r = 0; r < 4; ++r)
        bfeat[r] = bv[m0 + wy * 64 + mt * 16 + quad * 4 + r];
      for (int nt = 0; nt < 4; ++nt) {
        int n = n0 + wx * 64 + nt * 16 + l16;
        int b = n >> 11, tok = n & 2047;
        for (int r = 0; r < 4; ++r) {
          int f = m0 + wy * 64 + mt * 16 + quad * 4 + r;
          int h = f >> 6, dv = f & 63;
          Vt[(((size_t)(b * 16 + h) * 64 + dv) * SEQ) + tok] =
              f2bf(acc[mt][nt][r] + bfeat[r]);
        }
      }
    }
  }
}

// ---------------- out-projection GEMM + bias + residual (128x64 tiles) ----------------
__global__ __launch_bounds__(256) void gemm_o(
    const unsigned short* __restrict__ A, const unsigned short* __restrict__ Bt,
    const float* __restrict__ bias, const float* __restrict__ resid,
    float* __restrict__ Cout)
{
  __shared__ __align__(16) unsigned short sA[128 * 32];
  __shared__ __align__(16) unsigned short sB[64 * 32];
  const int tid = threadIdx.x;
  const int wave = tid >> 6, lane = tid & 63;
  const int quad = lane >> 4, l16 = lane & 15;
  const int wx = wave & 1, wy = wave >> 1;
  const int n0 = blockIdx.x * 64, m0 = blockIdx.y * 128;

  f32x4 acc[4][2];
  for (int mt = 0; mt < 4; ++mt)
    for (int nt = 0; nt < 2; ++nt) acc[mt][nt] = (f32x4){0.f, 0.f, 0.f, 0.f};

  const int rw = lane >> 2;
  const int cl = (((lane & 3) ^ ((lane >> 3) & 3))) * 8;
  const int g0 = (quad ^ ((l16 >> 1) & 3)) * 8;

  for (int k0 = 0; k0 < D_FEAT; k0 += 32) {
    __syncthreads();
    for (int j = 0; j < 2; ++j) {
      int ch = wave * 2 + j;
      gload16(A + (size_t)(m0 + ch * 16 + rw) * D_FEAT + k0 + cl, sA + ch * 512);
    }
    gload16(Bt + (size_t)(n0 + wave * 16 + rw) * D_FEAT + k0 + cl, sB + wave * 512);
    __syncthreads();
    s16x8 af[4], bfr[2];
    for (int mt = 0; mt < 4; ++mt)
      af[mt] = *(const s16x8*)(sA + (wy * 64 + mt * 16 + l16) * 32 + g0);
    for (int nt = 0; nt < 2; ++nt)
      bfr[nt] = *(const s16x8*)(sB + (wx * 32 + nt * 16 + l16) * 32 + g0);
    for (int mt = 0; mt < 4; ++mt)
      for (int nt = 0; nt < 2; ++nt)
        acc[mt][nt] = mfma16(af[mt], bfr[nt], acc[mt][nt]);
  }

  for (int mt = 0; mt < 4; ++mt)
    for (int nt = 0; nt < 2; ++nt) {
      int col = n0 + wx * 32 + nt * 16 + l16;
      float bcol = bias[col];
      for (int r = 0; r < 4; ++r) {
        int row = m0 + wy * 64 + mt * 16 + quad * 4 + r;
        Cout[(size_t)row * D_FEAT + col] =
            acc[mt][nt][r] + bcol + resid[(size_t)row * D_FEAT + col];
      }
    }
}

// ---------------- fused flash attention: 128q block, mfma32, O^T form ----------------
// grid (SEQ/128, B*NHEAD) = 512 blocks, 4 waves; wave owns q-strip of 32.
// S^T tiles D[key][q] (col=q=lane&31): softmax in-lane + one xor-32 shuffle.
// O^T tiles D[dv][q]: alpha/l are per-lane scalars. P via wave-private swizzled sP.
__global__ __launch_bounds__(256, 2) void flash_kernel(
    const unsigned short* __restrict__ Qp,
    const unsigned short* __restrict__ Kp,
    const unsigned short* __restrict__ Vt,
    unsigned short* __restrict__ ctx)
{
  __shared__ __align__(16) unsigned short sQ[128 * 64];  // reused as sP after hoist
  __shared__ __align__(16) unsigned short sK[64 * 64];
  __shared__ __align__(16) unsigned short sV[64 * 64];   // [dv][key]

  const int tid = threadIdx.x;
  const int wave = tid >> 6, lane = tid & 63;
  const int l32 = lane & 31, h = lane >> 5;
  const int q0 = blockIdx.x * 128;
  const int bh = blockIdx.y, b = bh >> 4, hd = bh & 15;
  const size_t base = (size_t)b * SEQ * D_FEAT + (size_t)hd * DK;
  const unsigned short* vt = Vt + (size_t)bh * 64 * SEQ;

  const int rw8 = lane >> 3;
  const int cls = ((lane & 7) ^ (lane >> 3)) * 8;   // swizzled source chunk

  // stage Q (128 x 64), swizzled: chunk c of row r at c ^ (r&7)
  for (int j = 0; j < 4; ++j) {
    int ch = wave * 4 + j;
    gload16(Qp + base + (size_t)(q0 + ch * 8 + rw8) * D_FEAT + cls, sQ + ch * 512);
  }
  __syncthreads();

  // hoist Q B-frags: n=q=qrow, slice s covers k=s*16+8h..+8
  const int qrow = wave * 32 + l32;
  const int qsw = qrow & 7;
  s16x8 bq[4];
  for (int s = 0; s < 4; ++s)
    bq[s] = *(const s16x8*)(sQ + qrow * 64 + ((2 * s + h) ^ qsw) * 8);

  unsigned short* sP = sQ;  // wave-private rows qrow

  f32x16 o0, o1;
  for (int r = 0; r < 16; ++r) { o0[r] = 0.f; o1[r] = 0.f; }
  float m_i = -INFINITY, l_i = 0.f;

  const int ksw0 = l32 & 7;  // (32+l32)&7 == l32&7

  for (int k0 = 0; k0 < SEQ; k0 += 64) {
    __syncthreads();  // prior-iter sK/sV reads done (incl. iter0: Q hoist done)
    for (int j = 0; j < 2; ++j) {
      int ch = wave * 2 + j;
      gload16(Kp + base + (size_t)(k0 + ch * 8 + rw8) * D_FEAT + cls, sK + ch * 512);
      gload16(vt + (size_t)(ch * 8 + rw8) * SEQ + k0 + cls, sV + ch * 512);
    }
    __syncthreads();

    // S^T: st0 = keys 0-31, st1 = keys 32-63 (rows), cols q
    f32x16 st0, st1;
    for (int r = 0; r < 16; ++r) { st0[r] = 0.f; st1[r] = 0.f; }
    for (int s = 0; s < 4; ++s) {
      int csw = ((2 * s + h) ^ ksw0) * 8;
      s16x8 a0 = *(const s16x8*)(sK + l32 * 64 + csw);
      s16x8 a1 = *(const s16x8*)(sK + (32 + l32) * 64 + csw);
      st0 = mfma32(a0, bq[s], st0);
      st1 = mfma32(a1, bq[s], st1);
    }

    // max over 32 in-lane scores + partner half (lane^32 has the other 32 keys)
    float mx = st0[0];
    for (int r = 0; r < 16; ++r) { mx = fmaxf(mx, st0[r]); mx = fmaxf(mx, st1[r]); }
    mx = fmaxf(mx, __shfl_xor(mx, 32, 64));
    float mn = fmaxf(m_i, mx);
    float alpha = __builtin_exp2f(m_i - mn);
    m_i = mn;

    // P = exp2(S^T - mn): pack to sP[q][key] (swizzled), accumulate sum
    float sum = 0.f;
    const int rowb = qrow * 64;
    for (int g = 0; g < 4; ++g) {
      unsigned int u[4];
      for (int r = 0; r < 4; ++r) {
        union { float f; unsigned int v; } x;
        x.f = __builtin_exp2f(st0[4 * g + r] - mn);
        sum += x.f; u[r] = x.v;
      }
      unsigned int w0 = __builtin_amdgcn_perm(u[1], u[0], 0x07060302u);
      unsigned int w1 = __builtin_amdgcn_perm(u[3], u[2], 0x07060302u);
      *(uint2*)(sP + rowb + ((g ^ qsw) * 8) + 4 * h) = make_uint2(w0, w1);
    }
    for (int g = 0; g < 4; ++g) {
      unsigned int u[4];
      for (int r = 0; r < 4; ++r) {
        union { float f; unsigned int v; } x;
        x.f = __builtin_exp2f(st1[4 * g + r] - mn);
        sum += x.f; u[r] = x.v;
      }
      unsigned int w0 = __builtin_amdgcn_perm(u[1], u[0], 0x07060302u);
      unsigned int w1 = __builtin_amdgcn_perm(u[3], u[2], 0x07060302u);
      *(uint2*)(sP + rowb + (((4 + g) ^ qsw) * 8) + 4 * h) = make_uint2(w0, w1);
    }
    sum += __shfl_xor(sum, 32, 64);
    l_i = l_i * alpha + sum;

    // rescale O (alpha is per-lane scalar: O^T cols = q = lane&31)
    for (int r = 0; r < 16; ++r) { o0[r] *= alpha; o1[r] *= alpha; }

    // P B-frags (same-wave LDS write->read, in-order)
    s16x8 bp[4];
    for (int s = 0; s < 4; ++s)
      bp[s] = *(const s16x8*)(sP + rowb + ((2 * s + h) ^ qsw) * 8);

    // O^T += V^T P : A = sV[dv][key]
    for (int s = 0; s < 4; ++s) {
      int csw = ((2 * s + h) ^ ksw0) * 8;
      s16x8 a0 = *(const s16x8*)(sV + l32 * 64 + csw);
      s16x8 a1 = *(const s16x8*)(sV + (32 + l32) * 64 + csw);
      o0 = mfma32(a0, bp[s], o0);
      o1 = mfma32(a1, bp[s], o1);
    }
  }

  // epilogue: O^T reg r -> dv=(r&3)+8*(r>>2)+4h (+32 for o1), token=q0+qrow
  float inv = __builtin_amdgcn_rcpf(l_i);
  unsigned short* crow = ctx + base + (size_t)(q0 + qrow) * D_FEAT;
  for (int g = 0; g < 4; ++g) {
    u16x4 ov;
    for (int r = 0; r < 4; ++r) ov[r] = f2bf(o0[4 * g + r] * inv);
    *(u16x4*)(crow + 8 * g + 4 * h) = ov;
  }
  for (int g = 0; g < 4; ++g) {
    u16x4 ov;
    for (int r = 0; r < 4; ++r) ov[r] = f2bf(o1[4 * g + r] * inv);
    *(u16x4*)(crow + 32 + 8 * g + 4 * h) = ov;
  }
}

// ---------------- LayerNorm over last dim (1024) ----------------
__global__ __launch_bounds__(256) void ln_kernel(
    const float* __restrict__ x, const float* __restrict__ gamma,
    const float* __restrict__ beta, float* __restrict__ out)
{
  const int row = blockIdx.x, tid = threadIdx.x;
  const int wave = tid >> 6, lane = tid & 63;
  const float* xr = x + (size_t)row * D_FEAT;
  float4 v = ((const float4*)xr)[tid];
  float s  = v.x + v.y + v.z + v.w;
  float ss = v.x * v.x + v.y * v.y + v.z * v.z + v.w * v.w;
  for (int off = 1; off < 64; off <<= 1) {
    s  += __shfl_xor(s,  off, 64);
    ss += __shfl_xor(ss, off, 64);
  }
  __shared__ float red[8];
  if (lane == 0) { red[wave] = s; red[wave + 4] = ss; }
  __syncthreads();
  s  = red[0] + red[1] + red[2] + red[3];
  ss = red[4] + red[5] + red[6] + red[7];
  float mean = s * (1.f / D_FEAT);
  float var  = ss * (1.f / D_FEAT) - mean * mean;
  float rstd = rsqrtf(var + 1e-6f);
  float4 g  = ((const float4*)gamma)[tid];
  float4 bt = ((const float4*)beta)[tid];
  float4 o;
  o.x = (v.x - mean) * rstd * g.x + bt.x;
  o.y = (v.y - mean) * rstd * g.y + bt.y;
  o.z = (v.z - mean) * rstd * g.z + bt.z;
  o.w = (v.w - mean) * rstd * g.w + bt.w;
  ((float4*)(out + (size_t)row * D_FEAT))[tid] = o;
}

extern "C" void kernel_launch(void* const* d_in, const int* in_sizes, int n_in,
                              void* d_out, int out_size, void* d_ws, size_t ws_size,
                              hipStream_t stream) {
  const float* q     = (const float*)d_in[0];
  const float* k     = (const float*)d_in[1];
  const float* v     = (const float*)d_in[2];
  const float* Wq    = (const float*)d_in[3];
  const float* bq    = (const float*)d_in[4];
  const float* Wk    = (const float*)d_in[5];
  const float* bk    = (const float*)d_in[6];
  const float* Wv    = (const float*)d_in[7];
  const float* bv    = (const float*)d_in[8];
  const float* Wo    = (const float*)d_in[9];
  const float* bo    = (const float*)d_in[10];
  const float* gamma = (const float*)d_in[11];
  const float* beta  = (const float*)d_in[12];

  char* w = (char*)d_ws;
  const size_t MB = 1u << 20;
  unsigned short* qb  = (unsigned short*)(w + 0 * MB);
  unsigned short* kb  = (unsigned short*)(w + 8 * MB);
  unsigned short* vb  = (unsigned short*)(w + 16 * MB);
  unsigned short* WT  = (unsigned short*)(w + 24 * MB);  // 6 MB: Wq^T|Wk^T|Wv^T
  unsigned short* Wot = (unsigned short*)(w + 30 * MB);
  unsigned short* Qp  = (unsigned short*)(w + 32 * MB);
  unsigned short* Kp  = (unsigned short*)(w + 40 * MB);
  unsigned short* Vt  = (unsigned short*)(w + 48 * MB);  // [bh][dv][tok]
  unsigned short* ctx = (unsigned short*)(w + 56 * MB);
  float*          tmp = (float*)(w + 64 * MB);

  cast_bf16_kernel<<<dim3(4096, 3), 256, 0, stream>>>(q, k, v, qb, kb, vb);
  transpose_cast_kernel<<<dim3(32, 32, 4), dim3(32, 8), 0, stream>>>(
      Wq, Wk, Wv, Wo, WT, Wot);

  gemm_qkv<<<dim3(24, 32), 256, 0, stream>>>(qb, kb, vb, WT, bq, bk, bv, Qp, Kp, Vt);

  flash_kernel<<<dim3(SEQ / 128, 32), 256, 0, stream>>>(Qp, Kp, Vt, ctx);

  gemm_o<<<dim3(16, 32), 256, 0, stream>>>(ctx, Wot, bo, v, tmp);

  ln_kernel<<<NTOK, 256, 0, stream>>>(tmp, gamma, beta, (float*)d_out);
}

// Round 5
// 254.112 us; speedup vs baseline: 1.5656x; 1.0957x over previous
//
#include <hip/hip_runtime.h>

#define D_FEAT 1024
#define NTOK   4096
#define SEQ    2048
#define NHEAD  16
#define DK     64
#define QSCALE 0.1803368801111204f  // 0.125 * log2(e)

typedef float          f32x4  __attribute__((ext_vector_type(4)));
typedef float          f32x16 __attribute__((ext_vector_type(16)));
typedef short          s16x8  __attribute__((ext_vector_type(8)));
typedef unsigned short u16x4  __attribute__((ext_vector_type(4)));

__device__ __forceinline__ unsigned short f2bf(float f) {
  union { float f; unsigned int u; } x; x.f = f;
  unsigned int r = x.u + 0x7fffu + ((x.u >> 16) & 1u);
  return (unsigned short)(r >> 16);
}
__device__ __forceinline__ unsigned short f2h(float f) {
  union { _Float16 h; unsigned short u; } x; x.h = (_Float16)f; return x.u;
}
__device__ __forceinline__ float h2f(unsigned short u) {
  union { _Float16 h; unsigned short u; } x; x.u = u; return (float)x.h;
}

__device__ __forceinline__ f32x4 mfma16(s16x8 a, s16x8 b, f32x4 c) {
  return __builtin_amdgcn_mfma_f32_16x16x32_bf16(a, b, c, 0, 0, 0);
}
__device__ __forceinline__ f32x16 mfma32(s16x8 a, s16x8 b, f32x16 c) {
  return __builtin_amdgcn_mfma_f32_32x32x16_bf16(a, b, c, 0, 0, 0);
}

// async global -> LDS, 16B per lane (dest = wave-uniform base + lane*16)
__device__ __forceinline__ void gload16(const void* g, void* l) {
  __builtin_amdgcn_global_load_lds(
      (const __attribute__((address_space(1))) void*)g,
      (__attribute__((address_space(3))) void*)l, 16, 0, 0);
}

// ---------------- prep: cast q/k/v to bf16 AND transpose+cast weights ----------------
// blocks [0,12288): cast (sel = bx>>12). blocks [12288,16384): weight transpose.
__global__ __launch_bounds__(256) void prep_kernel(
    const float* __restrict__ q, const float* __restrict__ k, const float* __restrict__ v,
    const float* __restrict__ Wq, const float* __restrict__ Wk,
    const float* __restrict__ Wv, const float* __restrict__ Wo,
    unsigned short* __restrict__ qb, unsigned short* __restrict__ kb,
    unsigned short* __restrict__ vb,
    unsigned short* __restrict__ WT, unsigned short* __restrict__ Wot)
{
  __shared__ float tile[32][33];
  const int bx = blockIdx.x, tid = threadIdx.x;
  if (bx < 12288) {
    int sel = bx >> 12;
    const float* src = sel == 0 ? q : (sel == 1 ? k : v);
    unsigned short* dst = sel == 0 ? qb : (sel == 1 ? kb : vb);
    size_t i = ((size_t)(bx & 4095) * 256 + tid) * 4;
    float4 f = *(const float4*)(src + i);
    u16x4 o; o.x = f2bf(f.x); o.y = f2bf(f.y); o.z = f2bf(f.z); o.w = f2bf(f.w);
    *(u16x4*)(dst + i) = o;
  } else {
    int t = bx - 12288;
    int z = t >> 10, rest = t & 1023;
    int bxt = rest & 31, byt = rest >> 5;
    const float* W = z == 0 ? Wq : z == 1 ? Wk : z == 2 ? Wv : Wo;
    unsigned short* T = (z < 3) ? (WT + (size_t)z * 1024 * 1024) : Wot;
    int tx = tid & 31, ty = tid >> 5;
    int n = bxt * 32 + tx;
    for (int i = 0; i < 4; ++i) {
      int kk = byt * 32 + ty + i * 8;
      tile[ty + i * 8][tx] = W[(size_t)kk * D_FEAT + n];
    }
    __syncthreads();
    int kk = byt * 32 + tx;
    for (int i = 0; i < 4; ++i) {
      int n2 = bxt * 32 + ty + i * 8;
      T[(size_t)n2 * D_FEAT + kk] = f2bf(tile[tx][ty + i * 8]);
    }
  }
}

// ---------------- fused QKV projection GEMM (BK=64) ----------------
// blocks x: 0-7 = Q proj (pre-scaled), 8-15 = K proj, 16-23 = V proj computed
// TRANSPOSED (M=features, N=tokens); V epilogue goes through LDS so Vt rows
// are written as coalesced 16B stores.
__global__ __launch_bounds__(256, 3) void gemm_qkv(
    const unsigned short* __restrict__ qb, const unsigned short* __restrict__ kb,
    const unsigned short* __restrict__ vb, const unsigned short* __restrict__ WT,
    const float* __restrict__ bq, const float* __restrict__ bk, const float* __restrict__ bv,
    unsigned short* __restrict__ Qp, unsigned short* __restrict__ Kp, unsigned short* __restrict__ Vt)
{
  __shared__ __align__(16) unsigned short sAB[2 * 128 * 64];
  unsigned short* sA = sAB;
  unsigned short* sB = sAB + 128 * 64;
  const int tid = threadIdx.x;
  const int wave = tid >> 6, lane = tid & 63;
  const int quad = lane >> 4, l16 = lane & 15;
  const int wx = wave & 1, wy = wave >> 1;
  const int bx = blockIdx.x;
  const int chunk = bx >> 3;

  const unsigned short* rA;
  const unsigned short* rB;
  int m0, n0;
  if (chunk < 2) {
    m0 = blockIdx.y * 128; n0 = (bx & 7) * 128;
    rA = (chunk ? kb : qb) + (size_t)m0 * D_FEAT;
    rB = WT + (size_t)(chunk * 1024 + n0) * D_FEAT;
  } else {
    m0 = (bx & 7) * 128; n0 = blockIdx.y * 128;
    rA = WT + (size_t)(2048 + m0) * D_FEAT;
    rB = vb + (size_t)n0 * D_FEAT;
  }

  f32x4 acc[4][4];
  for (int mt = 0; mt < 4; ++mt)
    for (int nt = 0; nt < 4; ++nt) acc[mt][nt] = (f32x4){0.f, 0.f, 0.f, 0.f};

  const int rw8 = lane >> 3;
  const int cls = ((lane & 7) ^ (lane >> 3)) * 8;  // swizzled source chunk
  const int sw = l16 & 7;

  for (int k0 = 0; k0 < D_FEAT; k0 += 64) {
    __syncthreads();
    for (int j = 0; j < 4; ++j) {
      int ch = wave * 4 + j;
      gload16(rA + (size_t)(ch * 8 + rw8) * D_FEAT + k0 + cls, sA + ch * 512);
      gload16(rB + (size_t)(ch * 8 + rw8) * D_FEAT + k0 + cls, sB + ch * 512);
    }
    __syncthreads();
    s16x8 af[2][4], bfr[2][4];
    for (int kk = 0; kk < 2; ++kk) {
      int c = ((kk * 4 + quad) ^ sw) * 8;
      for (int mt = 0; mt < 4; ++mt)
        af[kk][mt] = *(const s16x8*)(sA + (wy * 64 + mt * 16 + l16) * 64 + c);
      for (int nt = 0; nt < 4; ++nt)
        bfr[kk][nt] = *(const s16x8*)(sB + (wx * 64 + nt * 16 + l16) * 64 + c);
    }
    for (int kk = 0; kk < 2; ++kk)
      for (int mt = 0; mt < 4; ++mt)
        for (int nt = 0; nt < 4; ++nt)
          acc[mt][nt] = mfma16(af[kk][mt], bfr[kk][nt], acc[mt][nt]);
  }

  if (chunk < 2) {
    const float* bias = chunk ? bk : bq;
    unsigned short* Cp = chunk ? Kp : Qp;
    const float scale = chunk == 0 ? QSCALE : 1.0f;
    for (int mt = 0; mt < 4; ++mt)
      for (int nt = 0; nt < 4; ++nt) {
        int col = n0 + wx * 64 + nt * 16 + l16;
        float bcol = bias[col];
        for (int r = 0; r < 4; ++r) {
          int row = m0 + wy * 64 + mt * 16 + quad * 4 + r;
          Cp[(size_t)row * D_FEAT + col] = f2bf((acc[mt][nt][r] + bcol) * scale);
        }
      }
  } else {
    // bias (per feature = per m-row)
    for (int mt = 0; mt < 4; ++mt)
      for (int r = 0; r < 4; ++r) {
        float bfeat = bv[m0 + wy * 64 + mt * 16 + quad * 4 + r];
        for (int nt = 0; nt < 4; ++nt) acc[mt][nt][r] += bfeat;
      }
    // two passes (64 tokens each) through padded LDS [f 128][tok 64], stride 72
    unsigned short* tb = sAB;
    for (int p = 0; p < 2; ++p) {
      __syncthreads();
      if (wx == p) {
        for (int mt = 0; mt < 4; ++mt)
          for (int nt = 0; nt < 4; ++nt) {
            int tok_loc = nt * 16 + l16;
            for (int r = 0; r < 4; ++r) {
              int f_loc = wy * 64 + mt * 16 + quad * 4 + r;
              tb[f_loc * 72 + tok_loc] = f2bf(acc[mt][nt][r]);
            }
          }
      }
      __syncthreads();
      int n_base = n0 + p * 64;
      int b = n_base >> 11, tok0 = n_base & 2047;
      int ck = lane & 7;
      for (int j = 0; j < 4; ++j) {
        int f_loc = (wave * 4 + j) * 8 + rw8;
        int f = m0 + f_loc, hh = f >> 6, dv = f & 63;
        *(s16x8*)(Vt + ((size_t)(b * 16 + hh) * 64 + dv) * SEQ + tok0 + ck * 8) =
            *(const s16x8*)(tb + f_loc * 72 + ck * 8);
      }
    }
  }
}

// ---------------- out-projection GEMM + bias + residual (128x64 tiles, BK=64) ----------------
__global__ __launch_bounds__(256) void gemm_o(
    const unsigned short* __restrict__ A, const unsigned short* __restrict__ Bt,
    const float* __restrict__ bias, const float* __restrict__ resid,
    float* __restrict__ Cout)
{
  __shared__ __align__(16) unsigned short sA[128 * 64];
  __shared__ __align__(16) unsigned short sB[64 * 64];
  const int tid = threadIdx.x;
  const int wave = tid >> 6, lane = tid & 63;
  const int quad = lane >> 4, l16 = lane & 15;
  const int wx = wave & 1, wy = wave >> 1;
  const int n0 = blockIdx.x * 64, m0 = blockIdx.y * 128;

  f32x4 acc[4][2];
  for (int mt = 0; mt < 4; ++mt)
    for (int nt = 0; nt < 2; ++nt) acc[mt][nt] = (f32x4){0.f, 0.f, 0.f, 0.f};

  const int rw8 = lane >> 3;
  const int cls = ((lane & 7) ^ (lane >> 3)) * 8;
  const int sw = l16 & 7;

  for (int k0 = 0; k0 < D_FEAT; k0 += 64) {
    __syncthreads();
    for (int j = 0; j < 4; ++j) {
      int ch = wave * 4 + j;
      gload16(A + (size_t)(m0 + ch * 8 + rw8) * D_FEAT + k0 + cls, sA + ch * 512);
    }
    for (int j = 0; j < 2; ++j) {
      int ch = wave * 2 + j;
      gload16(Bt + (size_t)(n0 + ch * 8 + rw8) * D_FEAT + k0 + cls, sB + ch * 512);
    }
    __syncthreads();
    s16x8 af[2][4], bfr[2][2];
    for (int kk = 0; kk < 2; ++kk) {
      int c = ((kk * 4 + quad) ^ sw) * 8;
      for (int mt = 0; mt < 4; ++mt)
        af[kk][mt] = *(const s16x8*)(sA + (wy * 64 + mt * 16 + l16) * 64 + c);
      for (int nt = 0; nt < 2; ++nt)
        bfr[kk][nt] = *(const s16x8*)(sB + (wx * 32 + nt * 16 + l16) * 64 + c);
    }
    for (int kk = 0; kk < 2; ++kk)
      for (int mt = 0; mt < 4; ++mt)
        for (int nt = 0; nt < 2; ++nt)
          acc[mt][nt] = mfma16(af[kk][mt], bfr[kk][nt], acc[mt][nt]);
  }

  for (int mt = 0; mt < 4; ++mt)
    for (int nt = 0; nt < 2; ++nt) {
      int col = n0 + wx * 32 + nt * 16 + l16;
      float bcol = bias[col];
      for (int r = 0; r < 4; ++r) {
        int row = m0 + wy * 64 + mt * 16 + quad * 4 + r;
        Cout[(size_t)row * D_FEAT + col] =
            acc[mt][nt][r] + bcol + resid[(size_t)row * D_FEAT + col];
      }
    }
}

// ---------------- flash attention, split-S partial pass ----------------
// grid (SEQ/128, B*NHEAD, 2): z = key half. 4 waves; wave owns q-strip of 32.
// Outputs UNNORMALIZED O^T (fp16) + (m,l) per token per half.
__global__ __launch_bounds__(256, 4) void flash_part(
    const unsigned short* __restrict__ Qp,
    const unsigned short* __restrict__ Kp,
    const unsigned short* __restrict__ Vt,
    unsigned short* __restrict__ Opart,   // [z][bh][tok][dv] fp16
    float2* __restrict__ Ml)              // [z][bh][tok]
{
  __shared__ __align__(16) unsigned short sQ[128 * 64];  // reused as sP
  __shared__ __align__(16) unsigned short sK[64 * 64];
  __shared__ __align__(16) unsigned short sV[64 * 64];   // [dv][key]

  const int tid = threadIdx.x;
  const int wave = tid >> 6, lane = tid & 63;
  const int l32 = lane & 31, h = lane >> 5;
  const int q0 = blockIdx.x * 128;
  const int bh = blockIdx.y, b = bh >> 4, hd = bh & 15;
  const int z = blockIdx.z;
  const int kbase = z * (SEQ / 2);
  const size_t base = (size_t)b * SEQ * D_FEAT + (size_t)hd * DK;
  const unsigned short* vt = Vt + (size_t)bh * 64 * SEQ;

  const int rw8 = lane >> 3;
  const int cls = ((lane & 7) ^ (lane >> 3)) * 8;   // swizzled source chunk

  for (int j = 0; j < 4; ++j) {
    int ch = wave * 4 + j;
    gload16(Qp + base + (size_t)(q0 + ch * 8 + rw8) * D_FEAT + cls, sQ + ch * 512);
  }
  __syncthreads();

  const int qrow = wave * 32 + l32;
  const int qsw = qrow & 7;
  s16x8 bq[4];
  for (int s = 0; s < 4; ++s)
    bq[s] = *(const s16x8*)(sQ + qrow * 64 + ((2 * s + h) ^ qsw) * 8);

  unsigned short* sP = sQ;  // wave-private rows qrow

  f32x16 o0, o1;
  for (int r = 0; r < 16; ++r) { o0[r] = 0.f; o1[r] = 0.f; }
  float m_i = -INFINITY, l_i = 0.f;

  const int ksw0 = l32 & 7;

  for (int k0 = kbase; k0 < kbase + SEQ / 2; k0 += 64) {
    __syncthreads();
    for (int j = 0; j < 2; ++j) {
      int ch = wave * 2 + j;
      gload16(Kp + base + (size_t)(k0 + ch * 8 + rw8) * D_FEAT + cls, sK + ch * 512);
      gload16(vt + (size_t)(ch * 8 + rw8) * SEQ + k0 + cls, sV + ch * 512);
    }
    __syncthreads();

    f32x16 st0, st1;
    for (int r = 0; r < 16; ++r) { st0[r] = 0.f; st1[r] = 0.f; }
    for (int s = 0; s < 4; ++s) {
      int csw = ((2 * s + h) ^ ksw0) * 8;
      s16x8 a0 = *(const s16x8*)(sK + l32 * 64 + csw);
      s16x8 a1 = *(const s16x8*)(sK + (32 + l32) * 64 + csw);
      st0 = mfma32(a0, bq[s], st0);
      st1 = mfma32(a1, bq[s], st1);
    }

    float mx = st0[0];
    for (int r = 0; r < 16; ++r) { mx = fmaxf(mx, st0[r]); mx = fmaxf(mx, st1[r]); }
    mx = fmaxf(mx, __shfl_xor(mx, 32, 64));
    float mn = fmaxf(m_i, mx);
    float alpha = __builtin_exp2f(m_i - mn);
    m_i = mn;

    float sum = 0.f;
    const int rowb = qrow * 64;
    for (int g = 0; g < 4; ++g) {
      unsigned int u[4];
      for (int r = 0; r < 4; ++r) {
        union { float f; unsigned int v; } x;
        x.f = __builtin_exp2f(st0[4 * g + r] - mn);
        sum += x.f; u[r] = x.v;
      }
      unsigned int w0 = __builtin_amdgcn_perm(u[1], u[0], 0x07060302u);
      unsigned int w1 = __builtin_amdgcn_perm(u[3], u[2], 0x07060302u);
      *(uint2*)(sP + rowb + ((g ^ qsw) * 8) + 4 * h) = make_uint2(w0, w1);
    }
    for (int g = 0; g < 4; ++g) {
      unsigned int u[4];
      for (int r = 0; r < 4; ++r) {
        union { float f; unsigned int v; } x;
        x.f = __builtin_exp2f(st1[4 * g + r] - mn);
        sum += x.f; u[r] = x.v;
      }
      unsigned int w0 = __builtin_amdgcn_perm(u[1], u[0], 0x07060302u);
      unsigned int w1 = __builtin_amdgcn_perm(u[3], u[2], 0x07060302u);
      *(uint2*)(sP + rowb + (((4 + g) ^ qsw) * 8) + 4 * h) = make_uint2(w0, w1);
    }
    sum += __shfl_xor(sum, 32, 64);
    l_i = l_i * alpha + sum;

    for (int r = 0; r < 16; ++r) { o0[r] *= alpha; o1[r] *= alpha; }

    s16x8 bp[4];
    for (int s = 0; s < 4; ++s)
      bp[s] = *(const s16x8*)(sP + rowb + ((2 * s + h) ^ qsw) * 8);

    for (int s = 0; s < 4; ++s) {
      int csw = ((2 * s + h) ^ ksw0) * 8;
      s16x8 a0 = *(const s16x8*)(sV + l32 * 64 + csw);
      s16x8 a1 = *(const s16x8*)(sV + (32 + l32) * 64 + csw);
      o0 = mfma32(a0, bp[s], o0);
      o1 = mfma32(a1, bp[s], o1);
    }
  }

  // epilogue: unnormalized O^T (fp16) + (m,l)
  const size_t trow = (size_t)(z * 32 + bh) * SEQ + (q0 + qrow);
  unsigned short* orow = Opart + trow * 64;
  for (int g = 0; g < 4; ++g) {
    u16x4 ov;
    for (int r = 0; r < 4; ++r) ov[r] = f2h(o0[4 * g + r]);
    *(u16x4*)(orow + 8 * g + 4 * h) = ov;
  }
  for (int g = 0; g < 4; ++g) {
    u16x4 ov;
    for (int r = 0; r < 4; ++r) ov[r] = f2h(o1[4 * g + r]);
    *(u16x4*)(orow + 32 + 8 * g + 4 * h) = ov;
  }
  if (h == 0) Ml[trow] = make_float2(m_i, l_i);
}

// ---------------- combine the two key-halves -> ctx (bf16) ----------------
__global__ __launch_bounds__(256) void combine_kernel(
    const unsigned short* __restrict__ Opart, const float2* __restrict__ Ml,
    unsigned short* __restrict__ ctx)
{
  const int idx = blockIdx.x * 256 + threadIdx.x;   // 1M total
  const int dq = idx & 15;                          // dv group of 4
  const int trow = idx >> 4;                        // bh*SEQ + tok
  const int bh = trow >> 11, tok = trow & 2047;
  const int b = bh >> 4, h = bh & 15;
  const int HS = 32 * SEQ;                          // half stride (rows)

  float2 ml0 = Ml[trow], ml1 = Ml[HS + trow];
  float m = fmaxf(ml0.x, ml1.x);
  float w0 = __builtin_exp2f(ml0.x - m), w1 = __builtin_exp2f(ml1.x - m);
  float inv = __builtin_amdgcn_rcpf(ml0.y * w0 + ml1.y * w1);

  u16x4 p0 = *(const u16x4*)(Opart + (size_t)trow * 64 + dq * 4);
  u16x4 p1 = *(const u16x4*)(Opart + ((size_t)HS + trow) * 64 + dq * 4);
  u16x4 o;
  for (int r = 0; r < 4; ++r)
    o[r] = f2bf((h2f(p0[r]) * w0 + h2f(p1[r]) * w1) * inv);
  *(u16x4*)(ctx + (size_t)b * SEQ * D_FEAT + (size_t)tok * D_FEAT + h * 64 + dq * 4) = o;
}

// ---------------- LayerNorm over last dim (1024) ----------------
__global__ __launch_bounds__(256) void ln_kernel(
    const float* __restrict__ x, const float* __restrict__ gamma,
    const float* __restrict__ beta, float* __restrict__ out)
{
  const int row = blockIdx.x, tid = threadIdx.x;
  const int wave = tid >> 6, lane = tid & 63;
  const float* xr = x + (size_t)row * D_FEAT;
  float4 v = ((const float4*)xr)[tid];
  float s  = v.x + v.y + v.z + v.w;
  float ss = v.x * v.x + v.y * v.y + v.z * v.z + v.w * v.w;
  for (int off = 1; off < 64; off <<= 1) {
    s  += __shfl_xor(s,  off, 64);
    ss += __shfl_xor(ss, off, 64);
  }
  __shared__ float red[8];
  if (lane == 0) { red[wave] = s; red[wave + 4] = ss; }
  __syncthreads();
  s  = red[0] + red[1] + red[2] + red[3];
  ss = red[4] + red[5] + red[6] + red[7];
  float mean = s * (1.f / D_FEAT);
  float var  = ss * (1.f / D_FEAT) - mean * mean;
  float rstd = rsqrtf(var + 1e-6f);
  float4 g  = ((const float4*)gamma)[tid];
  float4 bt = ((const float4*)beta)[tid];
  float4 o;
  o.x = (v.x - mean) * rstd * g.x + bt.x;
  o.y = (v.y - mean) * rstd * g.y + bt.y;
  o.z = (v.z - mean) * rstd * g.z + bt.z;
  o.w = (v.w - mean) * rstd * g.w + bt.w;
  ((float4*)(out + (size_t)row * D_FEAT))[tid] = o;
}

extern "C" void kernel_launch(void* const* d_in, const int* in_sizes, int n_in,
                              void* d_out, int out_size, void* d_ws, size_t ws_size,
                              hipStream_t stream) {
  const float* q     = (const float*)d_in[0];
  const float* k     = (const float*)d_in[1];
  const float* v     = (const float*)d_in[2];
  const float* Wq    = (const float*)d_in[3];
  const float* bq    = (const float*)d_in[4];
  const float* Wk    = (const float*)d_in[5];
  const float* bk    = (const float*)d_in[6];
  const float* Wv    = (const float*)d_in[7];
  const float* bv    = (const float*)d_in[8];
  const float* Wo    = (const float*)d_in[9];
  const float* bo    = (const float*)d_in[10];
  const float* gamma = (const float*)d_in[11];
  const float* beta  = (const float*)d_in[12];

  char* w = (char*)d_ws;
  const size_t MB = 1u << 20;
  // phase 1 (prep + gemm_qkv): qb 0-8, kb 8-16, vb 16-24, WT 24-30
  // phase 2 (flash): Opart 0-16 (aliases qb/kb), Ml 16-17 (aliases vb) -- all dead
  unsigned short* qb    = (unsigned short*)(w + 0 * MB);
  unsigned short* kb    = (unsigned short*)(w + 8 * MB);
  unsigned short* vb    = (unsigned short*)(w + 16 * MB);
  unsigned short* WT    = (unsigned short*)(w + 24 * MB);
  unsigned short* Wot   = (unsigned short*)(w + 30 * MB);
  unsigned short* Qp    = (unsigned short*)(w + 32 * MB);
  unsigned short* Kp    = (unsigned short*)(w + 40 * MB);
  unsigned short* Vt    = (unsigned short*)(w + 48 * MB);  // [bh][dv][tok]
  unsigned short* ctx   = (unsigned short*)(w + 56 * MB);
  float*          tmp   = (float*)(w + 64 * MB);           // 16 MB
  unsigned short* Opart = (unsigned short*)(w + 0 * MB);   // 16 MB fp16
  float2*         Ml    = (float2*)(w + 16 * MB);          // 1 MB

  prep_kernel<<<16384, 256, 0, stream>>>(q, k, v, Wq, Wk, Wv, Wo, qb, kb, vb, WT, Wot);

  gemm_qkv<<<dim3(24, 32), 256, 0, stream>>>(qb, kb, vb, WT, bq, bk, bv, Qp, Kp, Vt);

  flash_part<<<dim3(SEQ / 128, 32, 2), 256, 0, stream>>>(Qp, Kp, Vt, Opart, Ml);

  combine_kernel<<<4096, 256, 0, stream>>>(Opart, Ml, ctx);

  gemm_o<<<dim3(16, 32), 256, 0, stream>>>(ctx, Wot, bo, v, tmp);

  ln_kernel<<<NTOK, 256, 0, stream>>>(tmp, gamma, beta, (float*)d_out);
}